// Round 8
// baseline (1626.434 us; speedup 1.0000x reference)
//
#include <hip/hip_runtime.h>
#include <hip/hip_bf16.h>

#define NEDGE 640000
#define NMAX  40000
#define SB    40      // scan blocks
#define PBLK  256     // pool blocks
#define EBLK  320     // edge-compact blocks
#define FB    1280    // fill blocks (128 thr each)
#define LIN1B 64      // lin1 partial blocks
#define GRB   32      // gemm rows per block
#define KT    16      // gemm K-tile
#define TKB   32      // fused top-k blocks

// ---------------------------------------------------------------- helpers
__device__ inline void atomicMaxF(float* addr, float val) {
    unsigned* ua = (unsigned*)addr;
    unsigned old = *ua;
    while (__uint_as_float(old) < val) {
        unsigned assumed = old;
        old = atomicCAS(ua, assumed, __float_as_uint(val));
        if (old == assumed) break;
    }
}

__device__ inline unsigned orderKey(float s) {
    unsigned b = __float_as_uint(s);
    return (b & 0x80000000u) ? ~b : (b | 0x80000000u);
}

// ballot-dedup LDS histogram insert: O(1) atomics per distinct bin per wave
__device__ inline void histAdd(int* sh, int bin, bool act, int nbits) {
    unsigned long long mm = __ballot(act);
    for (int b = 0; b < nbits; b++) {
        unsigned long long bal = __ballot(act && ((bin >> b) & 1));
        mm &= ((bin >> b) & 1) ? bal : ~bal;
    }
    if (act) {
        int lane = threadIdx.x & 63;
        int leader = __ffsll(mm) - 1;
        if (lane == leader) atomicAdd(&sh[bin], __popcll(mm));
    }
}

// grid barrier for co-resident blocks (fresh counter per use, zeroed in k_init)
__device__ inline void gridbar(int* ctr, int target) {
    __syncthreads();
    if (threadIdx.x == 0) {
        __threadfence();
        __hip_atomic_fetch_add(ctr, 1, __ATOMIC_RELEASE, __HIP_MEMORY_SCOPE_AGENT);
        while (__hip_atomic_load(ctr, __ATOMIC_ACQUIRE, __HIP_MEMORY_SCOPE_AGENT) < target)
            __builtin_amdgcn_s_sleep(1);
        __threadfence();
    }
    __syncthreads();
}

__device__ const float c_invk[10] = {
    1.0f/32000.0f, 1.0f/25600.0f, 1.0f/20480.0f, 1.0f/16384.0f, 1.0f/13108.0f,
    1.0f/10487.0f, 1.0f/8390.0f,  1.0f/6712.0f,  1.0f/5370.0f,  1.0f/4296.0f };

// selbuf slots: 0=bstar 1=rem 2=candcnt 3=thresh 4=cut 5=slotcnt

// ---------------------------------------------------------------- init (+ layer-0 degree count + ranks)
__global__ void k_init(const int* __restrict__ eidx, int* __restrict__ esrc,
                       int* __restrict__ edst, int* __restrict__ erank,
                       const float* __restrict__ poolp,
                       float* __restrict__ rbuf, float* __restrict__ pnorm,
                       int* __restrict__ ecnt, int* __restrict__ degA,
                       int* __restrict__ tkc) {
    int b = blockIdx.x, t = threadIdx.x;
    if (b < 10) {
        rbuf[b*256 + t] = (t < 128) ? -3.402823e38f : 0.0f;
        __shared__ float red[256];
        float v = 0.0f;
        if (t < 128) { float pv = poolp[b*128 + t]; v = pv*pv; }
        red[t] = v; __syncthreads();
        for (int s = 128; s > 0; s >>= 1) { if (t < s) red[t] += red[t+s]; __syncthreads(); }
        if (t == 0) pnorm[b] = sqrtf(red[0]);
    }
    if (b == 10 && t < 16) ecnt[t] = (t == 0) ? NEDGE : 0;
    if (b == 11 && t < 32) tkc[t] = 0;
    int e = b*256 + t;
    if (e < NEDGE) {
        int d = eidx[NEDGE + e];
        esrc[e] = eidx[e]; edst[e] = d;
        erank[e] = atomicAdd(&degA[d], 1);
    }
}

// ---------------------------------------------------------------- fused single-pass scan (decoupled lookback)
__global__ void k_scan(const int* __restrict__ deg,
                       int* __restrict__ offs, float* __restrict__ dinv,
                       int* __restrict__ ghist, int* __restrict__ selbuf,
                       int* __restrict__ lbsum, int* __restrict__ lbflag,
                       int n, int chunk, int epoch) {
    int b = blockIdx.x, t = threadIdx.x, lane = t & 63, wid = t >> 6;
    __shared__ int red[256];
    __shared__ int s_excl;
    __shared__ int wsum[4];
    __shared__ int s_carry;
    if (b == 0) {
        for (int jj = t; jj < 2048; jj += 256) ghist[jj] = 0;
        if (t == 0) { selbuf[2] = 0; selbuf[5] = 0; }
    }
    int start = b*chunk, end = min(start + chunk, n);
    int s = 0;
    for (int i = start + t; i < end; i += 256) s += deg[i];
    red[t] = s; __syncthreads();
    for (int st = 128; st > 0; st >>= 1) { if (t < st) red[t] += red[t+st]; __syncthreads(); }
    if (t == 0) {
        int total = red[0];
        int e1 = epoch*4 + 1, e2 = epoch*4 + 2;
        __hip_atomic_store(&lbsum[b*2], total, __ATOMIC_RELAXED, __HIP_MEMORY_SCOPE_AGENT);
        __hip_atomic_store(&lbflag[b], e1, __ATOMIC_RELEASE, __HIP_MEMORY_SCOPE_AGENT);
        int excl = 0;
        for (int p = b - 1; p >= 0; ) {
            int f;
            do { f = __hip_atomic_load(&lbflag[p], __ATOMIC_ACQUIRE, __HIP_MEMORY_SCOPE_AGENT); }
            while (f != e1 && f != e2);
            if (f == e2) { excl += __hip_atomic_load(&lbsum[p*2+1], __ATOMIC_RELAXED, __HIP_MEMORY_SCOPE_AGENT); break; }
            excl += __hip_atomic_load(&lbsum[p*2], __ATOMIC_RELAXED, __HIP_MEMORY_SCOPE_AGENT);
            p--;
        }
        __hip_atomic_store(&lbsum[b*2+1], excl + total, __ATOMIC_RELAXED, __HIP_MEMORY_SCOPE_AGENT);
        __hip_atomic_store(&lbflag[b], e2, __ATOMIC_RELEASE, __HIP_MEMORY_SCOPE_AGENT);
        s_excl = excl;
    }
    __syncthreads();
    if (t == 0) s_carry = s_excl;
    __syncthreads();
    for (int base = start; base < end; base += 256) {
        int i = base + t;
        int d = (i < end) ? deg[i] : 0;
        int incl = d;
        for (int off = 1; off < 64; off <<= 1) {
            int o = __shfl_up(incl, off);
            if (lane >= off) incl += o;
        }
        if (lane == 63) wsum[wid] = incl;
        __syncthreads();
        if (t == 0) { int c = s_carry; for (int w = 0; w < 4; w++) { int tmp = wsum[w]; wsum[w] = c; c += tmp; } s_carry = c; }
        __syncthreads();
        int p = wsum[wid] + incl - d;
        if (i < end) {
            offs[i] = p;
            dinv[i] = (d > 0) ? 1.0f/sqrtf((float)d) : 0.0f;
        }
        __syncthreads();
    }
}

// ---------------------------------------------------------------- fused CSR fill (rank-based, no atomics) + GEMM
__global__ __launch_bounds__(128) void k_fillgemm(const int* __restrict__ esrc, const int* __restrict__ edst,
        const int* __restrict__ erank, const int* __restrict__ offs,
        int* __restrict__ csr, const int* __restrict__ ecnt,
        const float* __restrict__ h, const float* __restrict__ W, const float* __restrict__ V,
        const float* __restrict__ bias, float* __restrict__ HW, float* __restrict__ AGG, int n) {
    int b = blockIdx.x, t = threadIdx.x;
    if (b < FB) {
        int ec = *ecnt;
        for (int e = b*128 + t; e < ec; e += FB*128) {
            csr[offs[edst[e]] + erank[e]] = esrc[e];
        }
        return;
    }
    __shared__ __align__(16) float ht[128*36];
    __shared__ __align__(16) float wt[KT*128];
    __shared__ __align__(16) float vt[KT*128];
    int v0 = (b - FB) * GRB;
    for (int it = 0; it < GRB; it++)
        ht[t*36 + it] = h[(size_t)(v0 + it)*128 + t];
    float accW[GRB], accV[GRB];
    #pragma unroll
    for (int r = 0; r < GRB; r++) { accW[r] = 0.0f; accV[r] = 0.0f; }
    for (int k0 = 0; k0 < 128; k0 += KT) {
        __syncthreads();
        const float4* Wp = (const float4*)(W + k0*128);
        const float4* Vp = (const float4*)(V + k0*128);
        float4* w4 = (float4*)wt;
        float4* v4 = (float4*)vt;
        #pragma unroll
        for (int q = 0; q < 4; q++) { w4[q*128 + t] = Wp[q*128 + t]; v4[q*128 + t] = Vp[q*128 + t]; }
        __syncthreads();
        for (int kk = 0; kk < KT; kk++) {
            float mw = wt[kk*128 + t];
            float mv = vt[kk*128 + t];
            const float* hp = &ht[(k0 + kk)*36];
            #pragma unroll
            for (int r4 = 0; r4 < GRB; r4 += 4) {
                float4 hq = *(const float4*)(hp + r4);
                accW[r4+0] += hq.x*mw;  accV[r4+0] += hq.x*mv;
                accW[r4+1] += hq.y*mw;  accV[r4+1] += hq.y*mv;
                accW[r4+2] += hq.z*mw;  accV[r4+2] += hq.z*mv;
                accW[r4+3] += hq.w*mw;  accV[r4+3] += hq.w*mv;
            }
        }
    }
    float bb = bias[t];
    for (int r = 0; r < GRB; r++) {
        int v = v0 + r;
        if (v >= n) break;
        HW[v*128 + t]  = accW[r];
        AGG[v*128 + t] = accV[r] + bb;
    }
}

// ---------------------------------------------------------------- layer-0 fused node update
__global__ __launch_bounds__(128) void k_gather0(
    const float* __restrict__ x, const float* __restrict__ W1, const float* __restrict__ V1,
    const float* __restrict__ convb,
    const float* __restrict__ bng, const float* __restrict__ bnb,
    const float* __restrict__ bnm, const float* __restrict__ bnv,
    const float* __restrict__ poolp, const float* __restrict__ pnorm,
    const float* __restrict__ prelua,
    const int* __restrict__ offs, const int* __restrict__ deg, const float* __restrict__ dinv,
    const int* __restrict__ csr,
    float* __restrict__ AGG, float* __restrict__ score, unsigned* __restrict__ keys) {
    int v = blockIdx.x, j = threadIdx.x;
    __shared__ float red[128];
    int off = offs[v], dg = deg[v];
    float accs = 0.0f;
    for (int c = j; c < dg; c += 128) { int s = csr[off + c]; accs += x[s]*dinv[s]; }
    red[j] = accs; __syncthreads();
    for (int st = 64; st > 0; st >>= 1) { if (j < st) red[j] += red[j+st]; __syncthreads(); }
    float aggs = red[0] * dinv[v];
    __syncthreads();
    float h2 = aggs*W1[j] + x[v]*V1[j] + convb[j];
    h2 = fmaxf(h2, 0.0f);
    float scale = bng[j] / sqrtf(bnv[j] + 1e-5f);
    h2 = (h2 - bnm[j])*scale + bnb[j];
    float a = prelua[0];
    h2 = (h2 > 0.0f) ? h2 : a*h2;
    AGG[v*128 + j] = h2;
    red[j] = h2 * poolp[j]; __syncthreads();
    for (int st = 64; st > 0; st >>= 1) { if (j < st) red[j] += red[j+st]; __syncthreads(); }
    if (j == 0) {
        float sc = tanhf(red[0] / pnorm[0]);
        score[v] = sc;
        keys[v]  = orderKey(sc);
    }
}

// ---------------------------------------------------------------- generic fused gather + update + score
__global__ __launch_bounds__(128) void k_gather(
    const float* __restrict__ HW, float* __restrict__ AGG,
    const int* __restrict__ offs, const int* __restrict__ deg, const float* __restrict__ dinv,
    const int* __restrict__ csr,
    const float* __restrict__ bng, const float* __restrict__ bnb,
    const float* __restrict__ bnm, const float* __restrict__ bnv,
    const float* __restrict__ poolp, const float* __restrict__ pnorm,
    const float* __restrict__ prelua,
    float* __restrict__ score, unsigned* __restrict__ keys, int layer) {
    int v = blockIdx.x, j = threadIdx.x;
    __shared__ int   s_src[128];
    __shared__ float s_dv[128];
    __shared__ float red[128];
    int off = offs[v], dg = deg[v];
    float acc = 0.0f;
    for (int base = 0; base < dg; base += 128) {
        int cnt = min(128, dg - base);
        if (j < cnt) { int s = csr[off + base + j]; s_src[j] = s; s_dv[j] = dinv[s]; }
        __syncthreads();
        for (int c = 0; c < cnt; c++) acc += HW[s_src[c]*128 + j] * s_dv[c];
        __syncthreads();
    }
    int gj = layer*128 + j;
    float h2 = AGG[v*128 + j] + acc*dinv[v];
    h2 = fmaxf(h2, 0.0f);
    float scale = bng[gj] / sqrtf(bnv[gj] + 1e-5f);
    h2 = (h2 - bnm[gj])*scale + bnb[gj];
    float a = prelua[0];
    h2 = (h2 > 0.0f) ? h2 : a*h2;
    AGG[v*128 + j] = h2;
    red[j] = h2 * poolp[gj]; __syncthreads();
    for (int st = 64; st > 0; st >>= 1) { if (j < st) red[j] += red[j+st]; __syncthreads(); }
    if (j == 0) {
        float sc = tanhf(red[0] / pnorm[layer]);
        score[v] = sc;
        keys[v]  = orderKey(sc);
    }
}

// ---------------------------------------------------------------- fused top-k: hist -> collect -> refine -> compact
// TKB blocks x 1024 thr, 3 internal grid barriers (all blocks co-resident).
__global__ __launch_bounds__(1024) void k_topk(const unsigned* __restrict__ keys,
                                               int* __restrict__ ghist, int* __restrict__ selbuf,
                                               unsigned* __restrict__ ckey, int* __restrict__ cidx,
                                               int* __restrict__ degN,
                                               int* __restrict__ remap, int* __restrict__ keep_ids,
                                               int* __restrict__ bar, int n, int kk) {
    __shared__ int lh[2048];
    __shared__ int s_bstar, s_rem, s_base, s_cur;
    int t = threadIdx.x, b = blockIdx.x, lane = t & 63;

    // ---- phase 1: zero degN + histogram (ballot-dedup)
    for (int i = b*1024 + t; i < NMAX; i += TKB*1024) degN[i] = 0;
    if (t < 2048) { lh[t] = 0; if (t < 1024) lh[t+1024] = 0; }
    lh[t] = 0; lh[t+1024] = 0;
    __syncthreads();
    int nR = (n + 1023) & ~1023;
    for (int i = b*1024 + t; i < nR; i += TKB*1024) {
        bool act = (i < n);
        int bin = act ? (int)(keys[i] >> 21) : 0;
        histAdd(lh, bin, act, 11);
    }
    __syncthreads();
    { int c0 = lh[t]; if (c0) atomicAdd(&ghist[t], c0);
      int c1 = lh[t+1024]; if (c1) atomicAdd(&ghist[t+1024], c1); }
    gridbar(&bar[0], TKB);

    // ---- phase 2: each block suffix-scans ghist, selects bin; collect candidates
    lh[t] = ghist[t]; lh[t+1024] = ghist[t+1024];
    __syncthreads();
    for (int off = 1; off < 2048; off <<= 1) {
        int v0 = lh[t]      + ((t+off < 2048)      ? lh[t+off]      : 0);
        int v1 = lh[t+1024] + ((t+1024+off < 2048) ? lh[t+1024+off] : 0);
        __syncthreads();
        lh[t] = v0; lh[t+1024] = v1;
        __syncthreads();
    }
    for (int d = t; d < 2048; d += 1024) {
        int S = lh[d], Sn = (d == 2047) ? 0 : lh[d+1];
        if (S >= kk && Sn < kk) {
            s_bstar = d; s_rem = kk - Sn;
            if (b == 0 && blockIdx.x == 0) { selbuf[0] = d; selbuf[1] = kk - Sn; }
        }
    }
    __syncthreads();
    int bstar = s_bstar;
    {
        int cnt = 0;
        for (int i = b*1024 + t; i < n; i += TKB*1024)
            cnt += ((int)(keys[i] >> 21) == bstar);
        // block reduce via lh
        lh[t] = cnt; __syncthreads();
        for (int st = 512; st > 0; st >>= 1) { if (t < st) lh[t] += lh[t+st]; __syncthreads(); }
        if (t == 0) { s_base = atomicAdd(&selbuf[2], lh[0]); s_cur = 0; }
        __syncthreads();
        for (int base = b*1024; base < n; base += TKB*1024) {
            int i = base + t;
            bool keep = false; unsigned key = 0;
            if (i < n) { key = keys[i]; keep = ((int)(key >> 21) == bstar); }
            unsigned long long m = __ballot(keep);
            int wcnt = __popcll(m);
            int wbase = 0;
            if (lane == 0 && wcnt) wbase = atomicAdd(&s_cur, wcnt);
            wbase = __shfl(wbase, 0);
            if (keep) {
                int pos = s_base + wbase + __popcll(m & ((1ULL << lane) - 1));
                ckey[pos] = key; cidx[pos] = i;
            }
        }
    }
    gridbar(&bar[1], TKB);

    // ---- phase 3: block 0 refines exact threshold + tie cutoff
    if (b == 0) {
        __shared__ int s_dA, s_remA, s_dB, s_ntk, s_bC, s_rem2, s_cut;
        int m = selbuf[2], rem = s_rem;
        int mR = (m + 1023) & ~1023;
        lh[t] = 0; lh[t+1024] = 0;
        __syncthreads();
        for (int i = t; i < mR; i += 1024) {
            bool act = (i < m);
            int bin = act ? (int)((ckey[i] >> 10) & 2047) : 0;
            histAdd(lh, bin, act, 11);
        }
        __syncthreads();
        for (int off = 1; off < 2048; off <<= 1) {
            int v0 = lh[t]      + ((t+off < 2048)      ? lh[t+off]      : 0);
            int v1 = lh[t+1024] + ((t+1024+off < 2048) ? lh[t+1024+off] : 0);
            __syncthreads();
            lh[t] = v0; lh[t+1024] = v1;
            __syncthreads();
        }
        for (int d = t; d < 2048; d += 1024) {
            int S = lh[d], Sn = (d == 2047) ? 0 : lh[d+1];
            if (S >= rem && Sn < rem) { s_dA = d; s_remA = rem - Sn; }
        }
        __syncthreads();
        int dA = s_dA, remA = s_remA;
        lh[t] = 0;
        __syncthreads();
        for (int i = t; i < mR; i += 1024) {
            bool act = (i < m) && ((int)((ckey[i] >> 10) & 2047) == dA);
            int bin = act ? (int)(ckey[i] & 1023) : 0;
            histAdd(lh, bin, act, 10);
        }
        __syncthreads();
        for (int off = 1; off < 1024; off <<= 1) {
            int v0 = lh[t] + ((t+off < 1024) ? lh[t+off] : 0);
            __syncthreads();
            lh[t] = v0;
            __syncthreads();
        }
        {
            int S = lh[t], Sn = (t == 1023) ? 0 : lh[t+1];
            if (S >= remA && Sn < remA) { s_dB = t; s_ntk = remA - Sn; }
        }
        __syncthreads();
        unsigned thresh = ((unsigned)bstar << 21) | ((unsigned)dA << 10) | (unsigned)s_dB;
        int ntk = s_ntk;
        if (t < 256) lh[t] = 0;
        __syncthreads();
        for (int i = t; i < mR; i += 1024) {
            bool act = (i < m) && (ckey[i] == thresh);
            int bin = act ? (cidx[i] >> 8) : 0;
            histAdd(lh, bin, act, 8);
        }
        __syncthreads();
        for (int off = 1; off < 256; off <<= 1) {
            int v = 0;
            if (t < 256) v = lh[t] + ((t >= off) ? lh[t-off] : 0);
            __syncthreads();
            if (t < 256) lh[t] = v;
            __syncthreads();
        }
        if (t < 256) {
            int P = lh[t], Pp = (t == 0) ? 0 : lh[t-1];
            if (P >= ntk && Pp < ntk) { s_bC = t; s_rem2 = ntk - Pp; }
        }
        __syncthreads();
        int bC = s_bC, rem2 = s_rem2;
        if (t < 256) lh[t] = 0;
        __syncthreads();
        for (int i = t; i < mR; i += 1024) {
            bool act = (i < m) && (ckey[i] == thresh) && ((cidx[i] >> 8) == bC);
            int bin = act ? (cidx[i] & 255) : 0;
            histAdd(lh, bin, act, 8);
        }
        __syncthreads();
        for (int off = 1; off < 256; off <<= 1) {
            int v = 0;
            if (t < 256) v = lh[t] + ((t >= off) ? lh[t-off] : 0);
            __syncthreads();
            if (t < 256) lh[t] = v;
            __syncthreads();
        }
        if (t < 256) {
            int P = lh[t], Pp = (t == 0) ? 0 : lh[t-1];
            if (P >= rem2 && Pp < rem2) s_cut = (bC << 8) | t;
        }
        __syncthreads();
        if (t == 0) { selbuf[3] = (int)thresh; selbuf[4] = s_cut; selbuf[5] = 0; }
    }
    gridbar(&bar[2], TKB);

    // ---- phase 4: compaction
    unsigned thresh = (unsigned)selbuf[3];
    int cut = selbuf[4];
    {
        int cnt = 0;
        for (int base = b*1024; base < n; base += TKB*1024) {
            int i = base + t;
            if (i < n) {
                unsigned key = keys[i];
                cnt += (key > thresh) || (key == thresh && i <= cut);
            }
        }
        lh[t] = cnt; __syncthreads();
        for (int st = 512; st > 0; st >>= 1) { if (t < st) lh[t] += lh[t+st]; __syncthreads(); }
        if (t == 0) { s_base = atomicAdd(&selbuf[5], lh[0]); s_cur = 0; }
        __syncthreads();
        for (int base = b*1024; base < n; base += TKB*1024) {
            int i = base + t;
            bool keep = false;
            if (i < n) {
                unsigned key = keys[i];
                keep = (key > thresh) || (key == thresh && i <= cut);
            }
            unsigned long long m = __ballot(keep);
            int wcnt = __popcll(m);
            int wbase = 0;
            if (lane == 0 && wcnt) wbase = atomicAdd(&s_cur, wcnt);
            wbase = __shfl(wbase, 0);
            if (keep) {
                int slot = s_base + wbase + __popcll(m & ((1ULL << lane) - 1));
                remap[i] = slot; keep_ids[slot] = i;
            } else if (i < n) remap[i] = -1;
        }
    }
}

// ---------------------------------------------------------------- pool + edge remap/compact (+next-layer degree/rank)
__global__ void k_pool(const float* __restrict__ AGG, const float* __restrict__ score,
                       const int* __restrict__ keep_ids, const int* __restrict__ remap,
                       float* __restrict__ H, float* __restrict__ rbuf,
                       const int* __restrict__ esrcP, const int* __restrict__ edstP,
                       int* __restrict__ esrcN, int* __restrict__ edstN, int* __restrict__ erankN,
                       const int* __restrict__ ecntP, int* __restrict__ ecntN,
                       int* __restrict__ degN, int k, int layer) {
    int b = blockIdx.x, t = threadIdx.x;
    if (b < PBLK) {
        int sub = t >> 7, j = t & 127;
        float lmax = -3.402823e38f, lsum = 0.0f;
        int s = b*2 + sub;
        int v = (s < k) ? keep_ids[s] : 0;
        while (s < k) {
            float sc = score[v];
            float val = AGG[v*128 + j] * sc;
            int s2 = s + PBLK*2;
            int v2 = (s2 < k) ? keep_ids[s2] : 0;
            H[s*128 + j] = val;
            lmax = fmaxf(lmax, val); lsum += val;
            s = s2; v = v2;
        }
        __shared__ float shm[256], shs[256];
        shm[t] = lmax; shs[t] = lsum;
        __syncthreads();
        if (sub == 0) {
            lmax = fmaxf(shm[j], shm[j+128]);
            lsum = shs[j] + shs[j+128];
            atomicMaxF(&rbuf[layer*256 + j], lmax);
            atomicAdd(&rbuf[layer*256 + 128 + j], lsum);
        }
    } else {
        int eb = b - PBLK, lane = t & 63;
        int ec = *ecntP;
        __shared__ int s_base, s_cur;
        __shared__ int red[256];
        int cnt = 0;
        for (int base = eb*256; base < ec; base += EBLK*256) {
            int e = base + t;
            if (e < ec) {
                int ns = remap[esrcP[e]], nd = remap[edstP[e]];
                cnt += (ns >= 0 && nd >= 0);
            }
        }
        red[t] = cnt; __syncthreads();
        for (int st = 128; st > 0; st >>= 1) { if (t < st) red[t] += red[t+st]; __syncthreads(); }
        if (t == 0) { s_base = atomicAdd(ecntN, red[0]); s_cur = 0; }
        __syncthreads();
        for (int base = eb*256; base < ec; base += EBLK*256) {
            int e = base + t;
            bool keep = false; int ns = 0, nd = 0;
            if (e < ec) {
                ns = remap[esrcP[e]]; nd = remap[edstP[e]];
                keep = (ns >= 0 && nd >= 0);
            }
            unsigned long long m = __ballot(keep);
            int wcnt = __popcll(m);
            int wbase = 0;
            if (lane == 0 && wcnt) wbase = atomicAdd(&s_cur, wcnt);
            wbase = __shfl(wbase, 0);
            if (keep) {
                int pos = s_base + wbase + __popcll(m & ((1ULL << lane) - 1));
                esrcN[pos] = ns; edstN[pos] = nd;
                erankN[pos] = atomicAdd(&degN[nd], 1);
            }
        }
    }
}

// ---------------------------------------------------------------- MLP head
__global__ __launch_bounds__(320) void k_lin1(const float* __restrict__ rbuf,
                                              const float* __restrict__ w1,
                                              float* __restrict__ z1part) {
    int b = blockIdx.x, t = threadIdx.x;
    int j = t*4;
    float4 acc = make_float4(0.f, 0.f, 0.f, 0.f);
    int i0 = b*40;
    for (int r = 0; r < 40; r++) {
        int i = i0 + r;
        float rv = rbuf[i];
        if (i & 128) rv *= c_invk[i >> 8];
        float4 w = *(const float4*)(w1 + (size_t)i*1280 + j);
        acc.x += rv*w.x; acc.y += rv*w.y; acc.z += rv*w.z; acc.w += rv*w.w;
    }
    *(float4*)(z1part + b*1280 + j) = acc;
}

__global__ __launch_bounds__(320) void k_lin2(const float* __restrict__ z1part,
                                              const float* __restrict__ b1,
                                              const float* __restrict__ w2, const float* __restrict__ b2,
                                              const float* __restrict__ prelua, float* __restrict__ out) {
    int t = threadIdx.x, lane = t & 63, wid = t >> 6;
    float a = prelua[0];
    int j = t*4;
    float4 acc = make_float4(0.f, 0.f, 0.f, 0.f);
    for (int p = 0; p < LIN1B; p++) {
        float4 v = *(const float4*)(z1part + p*1280 + j);
        acc.x += v.x; acc.y += v.y; acc.z += v.z; acc.w += v.w;
    }
    float4 bb = *(const float4*)(b1 + j);
    float z0 = acc.x + bb.x; z0 = z0 > 0.f ? z0 : a*z0;
    float z1 = acc.y + bb.y; z1 = z1 > 0.f ? z1 : a*z1;
    float z2 = acc.z + bb.z; z2 = z2 > 0.f ? z2 : a*z2;
    float z3 = acc.w + bb.w; z3 = z3 > 0.f ? z3 : a*z3;
    float s[8];
    #pragma unroll
    for (int o = 0; o < 8; o++)
        s[o] = z0*w2[(j+0)*8+o] + z1*w2[(j+1)*8+o] + z2*w2[(j+2)*8+o] + z3*w2[(j+3)*8+o];
    #pragma unroll
    for (int off = 32; off > 0; off >>= 1)
        #pragma unroll
        for (int o = 0; o < 8; o++) s[o] += __shfl_down(s[o], off);
    __shared__ float sred[5][8];
    if (lane == 0)
        for (int o = 0; o < 8; o++) sred[wid][o] = s[o];
    __syncthreads();
    if (t == 0) {
        float zo[8];
        for (int o = 0; o < 8; o++) {
            float z = sred[0][o]+sred[1][o]+sred[2][o]+sred[3][o]+sred[4][o] + b2[o];
            zo[o] = z > 0.f ? z : a*z;
        }
        float mn = zo[0];
        for (int o = 1; o < 8; o++) mn = fminf(mn, zo[o]);
        float v[8], mx = -3.402823e38f;
        for (int o = 0; o < 8; o++) { v[o] = zo[o] - mn; mx = fmaxf(mx, v[o]); }
        float sm = 0.f;
        for (int o = 0; o < 8; o++) { v[o] = v[o] / mx; sm += v[o]; }
        for (int o = 0; o < 8; o++) out[o] = v[o] / sm;
    }
}

// ---------------------------------------------------------------- launch
extern "C" void kernel_launch(void* const* d_in, const int* in_sizes, int n_in,
                              void* d_out, int out_size, void* d_ws, size_t ws_size,
                              hipStream_t stream) {
    const float* x      = (const float*)d_in[0];
    const int*   eidx   = (const int*)  d_in[1];
    const float* W1     = (const float*)d_in[2];
    const float* V1     = (const float*)d_in[3];
    const float* Ws     = (const float*)d_in[4];
    const float* Vs     = (const float*)d_in[5];
    const float* convb  = (const float*)d_in[6];
    const float* bng    = (const float*)d_in[7];
    const float* bnb    = (const float*)d_in[8];
    const float* bnm    = (const float*)d_in[9];
    const float* bnv    = (const float*)d_in[10];
    const float* poolp  = (const float*)d_in[11];
    const float* prelua = (const float*)d_in[12];
    const float* w1     = (const float*)d_in[13];
    const float* b1     = (const float*)d_in[14];
    const float* w2     = (const float*)d_in[15];
    const float* b2     = (const float*)d_in[16];
    float* out = (float*)d_out;

    float* wsf  = (float*)d_ws;
    float* H      = wsf;
    float* HW     = H     + (size_t)NMAX*128;
    float* AGG    = HW    + (size_t)NMAX*128;
    float* dinv   = AGG   + (size_t)NMAX*128;
    float* score  = dinv  + NMAX;
    float* rbuf   = score + NMAX;
    float* pnorm  = rbuf  + 2560;
    float* z1part = pnorm + 16;                  // LIN1B*1280
    unsigned* keys = (unsigned*)(z1part + LIN1B*1280);
    int* esrcA  = (int*)(keys + NMAX);
    int* edstA  = esrcA + NEDGE;
    int* erankA = edstA + NEDGE;
    int* esrcB  = erankA + NEDGE;
    int* edstB  = esrcB + NEDGE;
    int* erankB = edstB + NEDGE;
    int* csr    = erankB + NEDGE;
    int* degA   = csr   + NEDGE;
    int* degB   = degA  + NMAX;
    int* ghist  = degB  + NMAX;                  // 2048
    int* offs   = ghist + 2048;
    int* remap  = offs  + NMAX;
    int* keep_ids = remap + NMAX;
    unsigned* ckey = (unsigned*)(keep_ids + NMAX);
    int* cidx   = (int*)(ckey + NMAX);
    int* lbsum  = cidx  + NMAX;                  // SB*2
    int* lbflag = lbsum + SB*2;                  // SB
    int* ecnt   = lbflag + SB;                   // 16
    int* selbuf = ecnt  + 16;                    // 16
    int* tkc    = selbuf + 16;                   // 32 (topk barrier counters, 3/layer)

    static const int NS[10] = {40000,32000,25600,20480,16384,13108,10487,8390,6712,5370};
    static const int KS[10] = {32000,25600,20480,16384,13108,10487,8390,6712,5370,4296};

    hipMemsetAsync(degA, 0, (size_t)NMAX*sizeof(int), stream);
    k_init<<<2500, 256, 0, stream>>>(eidx, esrcA, edstA, erankA, poolp, rbuf, pnorm,
                                     ecnt, degA, tkc);

    for (int i = 0; i < 10; i++) {
        int n = NS[i], k = KS[i];
        int chunk = (n + SB - 1) / SB;
        int* esrcP  = (i & 1) ? esrcB  : esrcA;
        int* edstP  = (i & 1) ? edstB  : edstA;
        int* erankP = (i & 1) ? erankB : erankA;
        int* esrcN  = (i & 1) ? esrcA  : esrcB;
        int* edstN  = (i & 1) ? edstA  : edstB;
        int* erankN = (i & 1) ? erankA : erankB;
        int* degP   = (i & 1) ? degB : degA;
        int* degN   = (i & 1) ? degA : degB;

        k_scan<<<SB, 256, 0, stream>>>(degP, offs, dinv, ghist, selbuf,
                                       lbsum, lbflag, n, chunk, i + 1);

        int gb = (i == 0) ? 0 : (n + GRB - 1) / GRB;
        k_fillgemm<<<FB + gb, 128, 0, stream>>>(esrcP, edstP, erankP, offs, csr, &ecnt[i],
                                                H, (i == 0) ? W1 : Ws + (size_t)(i-1)*16384,
                                                (i == 0) ? V1 : Vs + (size_t)(i-1)*16384,
                                                convb + i*128, HW, AGG, n);

        if (i == 0) {
            k_gather0<<<n, 128, 0, stream>>>(x, W1, V1, convb,
                                             bng, bnb, bnm, bnv, poolp, pnorm, prelua,
                                             offs, degP, dinv, csr, AGG, score, keys);
        } else {
            k_gather<<<n, 128, 0, stream>>>(HW, AGG, offs, degP, dinv, csr,
                                            bng, bnb, bnm, bnv, poolp, pnorm, prelua,
                                            score, keys, i);
        }

        k_topk<<<TKB, 1024, 0, stream>>>(keys, ghist, selbuf, ckey, cidx, degN,
                                         remap, keep_ids, tkc + i*3, n, k);

        k_pool<<<PBLK + EBLK, 256, 0, stream>>>(AGG, score, keep_ids, remap, H, rbuf,
                                                esrcP, edstP, esrcN, edstN, erankN,
                                                &ecnt[i], &ecnt[i+1], degN, k, i);
    }

    k_lin1<<<LIN1B, 320, 0, stream>>>(rbuf, w1, z1part);
    k_lin2<<<1, 320, 0, stream>>>(z1part, b1, w2, b2, prelua, out);
}

// Round 9
// 1443.233 us; speedup vs baseline: 1.1269x; 1.1269x over previous
//
#include <hip/hip_runtime.h>
#include <hip/hip_bf16.h>

#define NEDGE 640000
#define NMAX  40000
#define SB    40      // scan blocks
#define PBLK  256     // pool blocks
#define EBLK  320     // edge-compact blocks
#define FB    1280    // fill blocks (128 thr each)
#define LIN1B 64      // lin1 partial blocks
#define GRB   32      // gemm rows per block
#define KT    16      // gemm K-tile
#define TKB   32      // fused top-k blocks
#define GHN   5632    // global hist ints (2048+2048+1024+256+256)

// ---------------------------------------------------------------- helpers
__device__ inline void atomicMaxF(float* addr, float val) {
    unsigned* ua = (unsigned*)addr;
    unsigned old = *ua;
    while (__uint_as_float(old) < val) {
        unsigned assumed = old;
        old = atomicCAS(ua, assumed, __float_as_uint(val));
        if (old == assumed) break;
    }
}

__device__ inline unsigned orderKey(float s) {
    unsigned b = __float_as_uint(s);
    return (b & 0x80000000u) ? ~b : (b | 0x80000000u);
}

// ballot-dedup LDS histogram insert: O(1) atomics per distinct bin per wave
__device__ inline void histAdd(int* sh, int bin, bool act, int nbits) {
    unsigned long long mm = __ballot(act);
    for (int b = 0; b < nbits; b++) {
        unsigned long long bal = __ballot(act && ((bin >> b) & 1));
        mm &= ((bin >> b) & 1) ? bal : ~bal;
    }
    if (act) {
        int lane = threadIdx.x & 63;
        int leader = __ffsll(mm) - 1;
        if (lane == leader) atomicAdd(&sh[bin], __popcll(mm));
    }
}

// grid barrier for co-resident blocks (fresh counter per use, zeroed in k_init)
__device__ inline void gridbar(int* ctr, int target) {
    __syncthreads();
    if (threadIdx.x == 0) {
        __threadfence();
        __hip_atomic_fetch_add(ctr, 1, __ATOMIC_RELEASE, __HIP_MEMORY_SCOPE_AGENT);
        while (__hip_atomic_load(ctr, __ATOMIC_ACQUIRE, __HIP_MEMORY_SCOPE_AGENT) < target)
            __builtin_amdgcn_s_sleep(1);
        __threadfence();
    }
    __syncthreads();
}

// per-block suffix-scan select over 2048-bin global hist (1024 threads)
__device__ inline void suffixSel2048(int* lh, const int* gh, int rem, int* outD, int* outR) {
    int t = threadIdx.x;
    lh[t] = gh[t]; lh[t+1024] = gh[t+1024];
    __syncthreads();
    for (int off = 1; off < 2048; off <<= 1) {
        int v0 = lh[t]      + ((t+off < 2048)      ? lh[t+off]      : 0);
        int v1 = lh[t+1024] + ((t+1024+off < 2048) ? lh[t+1024+off] : 0);
        __syncthreads();
        lh[t] = v0; lh[t+1024] = v1;
        __syncthreads();
    }
    for (int d = t; d < 2048; d += 1024) {
        int S = lh[d], Sn = (d == 2047) ? 0 : lh[d+1];
        if (S >= rem && Sn < rem) { *outD = d; *outR = rem - Sn; }
    }
    __syncthreads();
}

__device__ inline void suffixSel1024(int* lh, const int* gh, int rem, int* outD, int* outR) {
    int t = threadIdx.x;
    lh[t] = gh[t];
    __syncthreads();
    for (int off = 1; off < 1024; off <<= 1) {
        int v0 = lh[t] + ((t+off < 1024) ? lh[t+off] : 0);
        __syncthreads();
        lh[t] = v0;
        __syncthreads();
    }
    {
        int S = lh[t], Sn = (t == 1023) ? 0 : lh[t+1];
        if (S >= rem && Sn < rem) { *outD = t; *outR = rem - Sn; }
    }
    __syncthreads();
}

// ascending prefix select over 256-bin global hist
__device__ inline void prefixSel256(int* lh, const int* gh, int rem, int* outD, int* outR) {
    int t = threadIdx.x;
    if (t < 256) lh[t] = gh[t];
    __syncthreads();
    for (int off = 1; off < 256; off <<= 1) {
        int v = 0;
        if (t < 256) v = lh[t] + ((t >= off) ? lh[t-off] : 0);
        __syncthreads();
        if (t < 256) lh[t] = v;
        __syncthreads();
    }
    if (t < 256) {
        int P = lh[t], Pp = (t == 0) ? 0 : lh[t-1];
        if (P >= rem && Pp < rem) { *outD = t; *outR = rem - Pp; }
    }
    __syncthreads();
}

__device__ const float c_invk[10] = {
    1.0f/32000.0f, 1.0f/25600.0f, 1.0f/20480.0f, 1.0f/16384.0f, 1.0f/13108.0f,
    1.0f/10487.0f, 1.0f/8390.0f,  1.0f/6712.0f,  1.0f/5370.0f,  1.0f/4296.0f };

// ---------------------------------------------------------------- init (+ layer-0 degree count + ranks)
__global__ void k_init(const int* __restrict__ eidx, int* __restrict__ esrc,
                       int* __restrict__ edst, int* __restrict__ erank,
                       const float* __restrict__ poolp,
                       float* __restrict__ rbuf, float* __restrict__ pnorm,
                       int* __restrict__ ecnt, int* __restrict__ degA,
                       int* __restrict__ tkc) {
    int b = blockIdx.x, t = threadIdx.x;
    if (b < 10) {
        rbuf[b*256 + t] = (t < 128) ? -3.402823e38f : 0.0f;
        __shared__ float red[256];
        float v = 0.0f;
        if (t < 128) { float pv = poolp[b*128 + t]; v = pv*pv; }
        red[t] = v; __syncthreads();
        for (int s = 128; s > 0; s >>= 1) { if (t < s) red[t] += red[t+s]; __syncthreads(); }
        if (t == 0) pnorm[b] = sqrtf(red[0]);
    }
    if (b == 10 && t < 16) ecnt[t] = (t == 0) ? NEDGE : 0;
    if (b == 11 && t < 64) tkc[t] = 0;
    int e = b*256 + t;
    if (e < NEDGE) {
        int d = eidx[NEDGE + e];
        esrc[e] = eidx[e]; edst[e] = d;
        erank[e] = atomicAdd(&degA[d], 1);
    }
}

// ---------------------------------------------------------------- fused single-pass scan (decoupled lookback)
__global__ void k_scan(const int* __restrict__ deg,
                       int* __restrict__ offs, float* __restrict__ dinv,
                       int* __restrict__ ghist, int* __restrict__ selbuf,
                       int* __restrict__ lbsum, int* __restrict__ lbflag,
                       int n, int chunk, int epoch) {
    int b = blockIdx.x, t = threadIdx.x, lane = t & 63, wid = t >> 6;
    __shared__ int red[256];
    __shared__ int s_excl;
    __shared__ int wsum[4];
    __shared__ int s_carry;
    if (b == 0) {
        for (int jj = t; jj < GHN; jj += 256) ghist[jj] = 0;
        if (t == 0) { selbuf[2] = 0; selbuf[5] = 0; }
    }
    int start = b*chunk, end = min(start + chunk, n);
    int s = 0;
    for (int i = start + t; i < end; i += 256) s += deg[i];
    red[t] = s; __syncthreads();
    for (int st = 128; st > 0; st >>= 1) { if (t < st) red[t] += red[t+st]; __syncthreads(); }
    if (t == 0) {
        int total = red[0];
        int e1 = epoch*4 + 1, e2 = epoch*4 + 2;
        __hip_atomic_store(&lbsum[b*2], total, __ATOMIC_RELAXED, __HIP_MEMORY_SCOPE_AGENT);
        __hip_atomic_store(&lbflag[b], e1, __ATOMIC_RELEASE, __HIP_MEMORY_SCOPE_AGENT);
        int excl = 0;
        for (int p = b - 1; p >= 0; ) {
            int f;
            do { f = __hip_atomic_load(&lbflag[p], __ATOMIC_ACQUIRE, __HIP_MEMORY_SCOPE_AGENT); }
            while (f != e1 && f != e2);
            if (f == e2) { excl += __hip_atomic_load(&lbsum[p*2+1], __ATOMIC_RELAXED, __HIP_MEMORY_SCOPE_AGENT); break; }
            excl += __hip_atomic_load(&lbsum[p*2], __ATOMIC_RELAXED, __HIP_MEMORY_SCOPE_AGENT);
            p--;
        }
        __hip_atomic_store(&lbsum[b*2+1], excl + total, __ATOMIC_RELAXED, __HIP_MEMORY_SCOPE_AGENT);
        __hip_atomic_store(&lbflag[b], e2, __ATOMIC_RELEASE, __HIP_MEMORY_SCOPE_AGENT);
        s_excl = excl;
    }
    __syncthreads();
    if (t == 0) s_carry = s_excl;
    __syncthreads();
    for (int base = start; base < end; base += 256) {
        int i = base + t;
        int d = (i < end) ? deg[i] : 0;
        int incl = d;
        for (int off = 1; off < 64; off <<= 1) {
            int o = __shfl_up(incl, off);
            if (lane >= off) incl += o;
        }
        if (lane == 63) wsum[wid] = incl;
        __syncthreads();
        if (t == 0) { int c = s_carry; for (int w = 0; w < 4; w++) { int tmp = wsum[w]; wsum[w] = c; c += tmp; } s_carry = c; }
        __syncthreads();
        int p = wsum[wid] + incl - d;
        if (i < end) {
            offs[i] = p;
            dinv[i] = (d > 0) ? 1.0f/sqrtf((float)d) : 0.0f;
        }
        __syncthreads();
    }
}

// ---------------------------------------------------------------- fused CSR fill (rank-based, no atomics) + GEMM
__global__ __launch_bounds__(128) void k_fillgemm(const int* __restrict__ esrc, const int* __restrict__ edst,
        const int* __restrict__ erank, const int* __restrict__ offs,
        int* __restrict__ csr, const int* __restrict__ ecnt,
        const float* __restrict__ h, const float* __restrict__ W, const float* __restrict__ V,
        const float* __restrict__ bias, float* __restrict__ HW, float* __restrict__ AGG, int n) {
    int b = blockIdx.x, t = threadIdx.x;
    if (b < FB) {
        int ec = *ecnt;
        for (int e = b*128 + t; e < ec; e += FB*128) {
            csr[offs[edst[e]] + erank[e]] = esrc[e];
        }
        return;
    }
    __shared__ __align__(16) float ht[128*36];
    __shared__ __align__(16) float wt[KT*128];
    __shared__ __align__(16) float vt[KT*128];
    int v0 = (b - FB) * GRB;
    for (int it = 0; it < GRB; it++)
        ht[t*36 + it] = h[(size_t)(v0 + it)*128 + t];
    float accW[GRB], accV[GRB];
    #pragma unroll
    for (int r = 0; r < GRB; r++) { accW[r] = 0.0f; accV[r] = 0.0f; }
    for (int k0 = 0; k0 < 128; k0 += KT) {
        __syncthreads();
        const float4* Wp = (const float4*)(W + k0*128);
        const float4* Vp = (const float4*)(V + k0*128);
        float4* w4 = (float4*)wt;
        float4* v4 = (float4*)vt;
        #pragma unroll
        for (int q = 0; q < 4; q++) { w4[q*128 + t] = Wp[q*128 + t]; v4[q*128 + t] = Vp[q*128 + t]; }
        __syncthreads();
        for (int kk = 0; kk < KT; kk++) {
            float mw = wt[kk*128 + t];
            float mv = vt[kk*128 + t];
            const float* hp = &ht[(k0 + kk)*36];
            #pragma unroll
            for (int r4 = 0; r4 < GRB; r4 += 4) {
                float4 hq = *(const float4*)(hp + r4);
                accW[r4+0] += hq.x*mw;  accV[r4+0] += hq.x*mv;
                accW[r4+1] += hq.y*mw;  accV[r4+1] += hq.y*mv;
                accW[r4+2] += hq.z*mw;  accV[r4+2] += hq.z*mv;
                accW[r4+3] += hq.w*mw;  accV[r4+3] += hq.w*mv;
            }
        }
    }
    float bb = bias[t];
    for (int r = 0; r < GRB; r++) {
        int v = v0 + r;
        if (v >= n) break;
        HW[v*128 + t]  = accW[r];
        AGG[v*128 + t] = accV[r] + bb;
    }
}

// ---------------------------------------------------------------- layer-0 fused node update
__global__ __launch_bounds__(128) void k_gather0(
    const float* __restrict__ x, const float* __restrict__ W1, const float* __restrict__ V1,
    const float* __restrict__ convb,
    const float* __restrict__ bng, const float* __restrict__ bnb,
    const float* __restrict__ bnm, const float* __restrict__ bnv,
    const float* __restrict__ poolp, const float* __restrict__ pnorm,
    const float* __restrict__ prelua,
    const int* __restrict__ offs, const int* __restrict__ deg, const float* __restrict__ dinv,
    const int* __restrict__ csr,
    float* __restrict__ AGG, float* __restrict__ score, unsigned* __restrict__ keys) {
    int v = blockIdx.x, j = threadIdx.x;
    __shared__ float red[128];
    int off = offs[v], dg = deg[v];
    float accs = 0.0f;
    for (int c = j; c < dg; c += 128) { int s = csr[off + c]; accs += x[s]*dinv[s]; }
    red[j] = accs; __syncthreads();
    for (int st = 64; st > 0; st >>= 1) { if (j < st) red[j] += red[j+st]; __syncthreads(); }
    float aggs = red[0] * dinv[v];
    __syncthreads();
    float h2 = aggs*W1[j] + x[v]*V1[j] + convb[j];
    h2 = fmaxf(h2, 0.0f);
    float scale = bng[j] / sqrtf(bnv[j] + 1e-5f);
    h2 = (h2 - bnm[j])*scale + bnb[j];
    float a = prelua[0];
    h2 = (h2 > 0.0f) ? h2 : a*h2;
    AGG[v*128 + j] = h2;
    red[j] = h2 * poolp[j]; __syncthreads();
    for (int st = 64; st > 0; st >>= 1) { if (j < st) red[j] += red[j+st]; __syncthreads(); }
    if (j == 0) {
        float sc = tanhf(red[0] / pnorm[0]);
        score[v] = sc;
        keys[v]  = orderKey(sc);
    }
}

// ---------------------------------------------------------------- generic fused gather + update + score
__global__ __launch_bounds__(128) void k_gather(
    const float* __restrict__ HW, float* __restrict__ AGG,
    const int* __restrict__ offs, const int* __restrict__ deg, const float* __restrict__ dinv,
    const int* __restrict__ csr,
    const float* __restrict__ bng, const float* __restrict__ bnb,
    const float* __restrict__ bnm, const float* __restrict__ bnv,
    const float* __restrict__ poolp, const float* __restrict__ pnorm,
    const float* __restrict__ prelua,
    float* __restrict__ score, unsigned* __restrict__ keys, int layer) {
    int v = blockIdx.x, j = threadIdx.x;
    __shared__ int   s_src[128];
    __shared__ float s_dv[128];
    __shared__ float red[128];
    int off = offs[v], dg = deg[v];
    float acc = 0.0f;
    for (int base = 0; base < dg; base += 128) {
        int cnt = min(128, dg - base);
        if (j < cnt) { int s = csr[off + base + j]; s_src[j] = s; s_dv[j] = dinv[s]; }
        __syncthreads();
        for (int c = 0; c < cnt; c++) acc += HW[s_src[c]*128 + j] * s_dv[c];
        __syncthreads();
    }
    int gj = layer*128 + j;
    float h2 = AGG[v*128 + j] + acc*dinv[v];
    h2 = fmaxf(h2, 0.0f);
    float scale = bng[gj] / sqrtf(bnv[gj] + 1e-5f);
    h2 = (h2 - bnm[gj])*scale + bnb[gj];
    float a = prelua[0];
    h2 = (h2 > 0.0f) ? h2 : a*h2;
    AGG[v*128 + j] = h2;
    red[j] = h2 * poolp[gj]; __syncthreads();
    for (int st = 64; st > 0; st >>= 1) { if (j < st) red[j] += red[j+st]; __syncthreads(); }
    if (j == 0) {
        float sc = tanhf(red[0] / pnorm[layer]);
        score[v] = sc;
        keys[v]  = orderKey(sc);
    }
}

// ---------------------------------------------------------------- fused top-k, all phases grid-parallel
// 5 grid-parallel histogram passes over keys + redundant per-block selects.
__global__ __launch_bounds__(1024) void k_topk(const unsigned* __restrict__ keys,
                                               int* __restrict__ gh, int* __restrict__ selbuf,
                                               int* __restrict__ degN,
                                               int* __restrict__ remap, int* __restrict__ keep_ids,
                                               int* __restrict__ bar, int n, int kk) {
    __shared__ int lh[2048];
    __shared__ int s_d1, s_r1, s_dA, s_rA, s_dB, s_ntk, s_bC, s_r2, s_lowD, s_lowR;
    __shared__ int s_base, s_cur;
    int t = threadIdx.x, b = blockIdx.x, lane = t & 63;
    int* h1 = gh;          // 2048: key>>21
    int* h2 = gh + 2048;   // 2048: (key>>10)&2047 within bstar
    int* h3 = gh + 4096;   // 1024: key&1023 within top-21
    int* h4 = gh + 5120;   // 256:  idx>>8 of ties
    int* h5 = gh + 5376;   // 256:  idx&255 of ties in bC

    for (int i = b*1024 + t; i < NMAX; i += TKB*1024) degN[i] = 0;

    int nR = (n + 1023) & ~1023;
    // ---- phase 1: hist of top 11 bits
    lh[t] = 0; lh[t+1024] = 0;
    __syncthreads();
    for (int i = b*1024 + t; i < nR; i += TKB*1024) {
        bool act = (i < n);
        int bin = act ? (int)(keys[i] >> 21) : 0;
        histAdd(lh, bin, act, 11);
    }
    __syncthreads();
    { int c = lh[t]; if (c) atomicAdd(&h1[t], c); c = lh[t+1024]; if (c) atomicAdd(&h1[t+1024], c); }
    gridbar(&bar[0], TKB);
    suffixSel2048(lh, h1, kk, &s_d1, &s_r1);
    int bstar = s_d1;

    // ---- phase 2: bits 20..10 within bstar
    lh[t] = 0; lh[t+1024] = 0;
    __syncthreads();
    for (int i = b*1024 + t; i < nR; i += TKB*1024) {
        bool act = false; int bin = 0;
        if (i < n) { unsigned key = keys[i]; act = ((int)(key >> 21) == bstar); bin = (int)((key >> 10) & 2047); }
        histAdd(lh, act ? bin : 0, act, 11);
    }
    __syncthreads();
    { int c = lh[t]; if (c) atomicAdd(&h2[t], c); c = lh[t+1024]; if (c) atomicAdd(&h2[t+1024], c); }
    gridbar(&bar[1], TKB);
    suffixSel2048(lh, h2, s_r1, &s_dA, &s_rA);
    unsigned top21 = ((unsigned)bstar << 11) | (unsigned)s_dA;

    // ---- phase 3: bits 9..0 within top-21
    lh[t] = 0;
    __syncthreads();
    for (int i = b*1024 + t; i < nR; i += TKB*1024) {
        bool act = false; int bin = 0;
        if (i < n) { unsigned key = keys[i]; act = ((key >> 10) == top21); bin = (int)(key & 1023); }
        histAdd(lh, act ? bin : 0, act, 10);
    }
    __syncthreads();
    { int c = lh[t]; if (c) atomicAdd(&h3[t], c); }
    gridbar(&bar[2], TKB);
    suffixSel1024(lh, h3, s_rA, &s_dB, &s_ntk);
    unsigned thresh = (top21 << 10) | (unsigned)s_dB;

    // ---- phase 4: tie idx high byte (plain LDS atomics: bins spread)
    if (t < 256) lh[t] = 0;
    __syncthreads();
    for (int i = b*1024 + t; i < n; i += TKB*1024)
        if (keys[i] == thresh) atomicAdd(&lh[i >> 8], 1);
    __syncthreads();
    if (t < 256) { int c = lh[t]; if (c) atomicAdd(&h4[t], c); }
    gridbar(&bar[3], TKB);
    prefixSel256(lh, h4, s_ntk, &s_bC, &s_r2);
    int bC = s_bC;

    // ---- phase 5: tie idx low byte within bC
    if (t < 256) lh[t] = 0;
    __syncthreads();
    for (int i = b*1024 + t; i < n; i += TKB*1024)
        if (keys[i] == thresh && (i >> 8) == bC) atomicAdd(&lh[i & 255], 1);
    __syncthreads();
    if (t < 256) { int c = lh[t]; if (c) atomicAdd(&h5[t], c); }
    gridbar(&bar[4], TKB);
    prefixSel256(lh, h5, s_r2, &s_lowD, &s_lowR);
    int cut = (bC << 8) | s_lowD;

    // ---- phase 6: compaction (two-phase block-aggregated)
    {
        int cnt = 0;
        for (int base = b*1024; base < n; base += TKB*1024) {
            int i = base + t;
            if (i < n) {
                unsigned key = keys[i];
                cnt += (key > thresh) || (key == thresh && i <= cut);
            }
        }
        lh[t] = cnt; __syncthreads();
        for (int st = 512; st > 0; st >>= 1) { if (t < st) lh[t] += lh[t+st]; __syncthreads(); }
        if (t == 0) { s_base = atomicAdd(&selbuf[5], lh[0]); s_cur = 0; }
        __syncthreads();
        for (int base = b*1024; base < n; base += TKB*1024) {
            int i = base + t;
            bool keep = false;
            if (i < n) {
                unsigned key = keys[i];
                keep = (key > thresh) || (key == thresh && i <= cut);
            }
            unsigned long long m = __ballot(keep);
            int wcnt = __popcll(m);
            int wbase = 0;
            if (lane == 0 && wcnt) wbase = atomicAdd(&s_cur, wcnt);
            wbase = __shfl(wbase, 0);
            if (keep) {
                int slot = s_base + wbase + __popcll(m & ((1ULL << lane) - 1));
                remap[i] = slot; keep_ids[slot] = i;
            } else if (i < n) remap[i] = -1;
        }
    }
}

// ---------------------------------------------------------------- pool + edge remap/compact (+next-layer degree/rank)
__global__ void k_pool(const float* __restrict__ AGG, const float* __restrict__ score,
                       const int* __restrict__ keep_ids, const int* __restrict__ remap,
                       float* __restrict__ H, float* __restrict__ rbuf,
                       const int* __restrict__ esrcP, const int* __restrict__ edstP,
                       int* __restrict__ esrcN, int* __restrict__ edstN, int* __restrict__ erankN,
                       const int* __restrict__ ecntP, int* __restrict__ ecntN,
                       int* __restrict__ degN, int k, int layer) {
    int b = blockIdx.x, t = threadIdx.x;
    if (b < PBLK) {
        int sub = t >> 7, j = t & 127;
        float lmax = -3.402823e38f, lsum = 0.0f;
        int s = b*2 + sub;
        int v = (s < k) ? keep_ids[s] : 0;
        while (s < k) {
            float sc = score[v];
            float val = AGG[v*128 + j] * sc;
            int s2 = s + PBLK*2;
            int v2 = (s2 < k) ? keep_ids[s2] : 0;
            H[s*128 + j] = val;
            lmax = fmaxf(lmax, val); lsum += val;
            s = s2; v = v2;
        }
        __shared__ float shm[256], shs[256];
        shm[t] = lmax; shs[t] = lsum;
        __syncthreads();
        if (sub == 0) {
            lmax = fmaxf(shm[j], shm[j+128]);
            lsum = shs[j] + shs[j+128];
            atomicMaxF(&rbuf[layer*256 + j], lmax);
            atomicAdd(&rbuf[layer*256 + 128 + j], lsum);
        }
    } else {
        int eb = b - PBLK, lane = t & 63;
        int ec = *ecntP;
        __shared__ int s_base, s_cur;
        __shared__ int red[256];
        int cnt = 0;
        for (int base = eb*256; base < ec; base += EBLK*256) {
            int e = base + t;
            if (e < ec) {
                int ns = remap[esrcP[e]], nd = remap[edstP[e]];
                cnt += (ns >= 0 && nd >= 0);
            }
        }
        red[t] = cnt; __syncthreads();
        for (int st = 128; st > 0; st >>= 1) { if (t < st) red[t] += red[t+st]; __syncthreads(); }
        if (t == 0) { s_base = atomicAdd(ecntN, red[0]); s_cur = 0; }
        __syncthreads();
        for (int base = eb*256; base < ec; base += EBLK*256) {
            int e = base + t;
            bool keep = false; int ns = 0, nd = 0;
            if (e < ec) {
                ns = remap[esrcP[e]]; nd = remap[edstP[e]];
                keep = (ns >= 0 && nd >= 0);
            }
            unsigned long long m = __ballot(keep);
            int wcnt = __popcll(m);
            int wbase = 0;
            if (lane == 0 && wcnt) wbase = atomicAdd(&s_cur, wcnt);
            wbase = __shfl(wbase, 0);
            if (keep) {
                int pos = s_base + wbase + __popcll(m & ((1ULL << lane) - 1));
                esrcN[pos] = ns; edstN[pos] = nd;
                erankN[pos] = atomicAdd(&degN[nd], 1);
            }
        }
    }
}

// ---------------------------------------------------------------- MLP head
__global__ __launch_bounds__(320) void k_lin1(const float* __restrict__ rbuf,
                                              const float* __restrict__ w1,
                                              float* __restrict__ z1part) {
    int b = blockIdx.x, t = threadIdx.x;
    int j = t*4;
    float4 acc = make_float4(0.f, 0.f, 0.f, 0.f);
    int i0 = b*40;
    for (int r = 0; r < 40; r++) {
        int i = i0 + r;
        float rv = rbuf[i];
        if (i & 128) rv *= c_invk[i >> 8];
        float4 w = *(const float4*)(w1 + (size_t)i*1280 + j);
        acc.x += rv*w.x; acc.y += rv*w.y; acc.z += rv*w.z; acc.w += rv*w.w;
    }
    *(float4*)(z1part + b*1280 + j) = acc;
}

__global__ __launch_bounds__(320) void k_lin2(const float* __restrict__ z1part,
                                              const float* __restrict__ b1,
                                              const float* __restrict__ w2, const float* __restrict__ b2,
                                              const float* __restrict__ prelua, float* __restrict__ out) {
    int t = threadIdx.x, lane = t & 63, wid = t >> 6;
    float a = prelua[0];
    int j = t*4;
    float4 acc = make_float4(0.f, 0.f, 0.f, 0.f);
    for (int p = 0; p < LIN1B; p++) {
        float4 v = *(const float4*)(z1part + p*1280 + j);
        acc.x += v.x; acc.y += v.y; acc.z += v.z; acc.w += v.w;
    }
    float4 bb = *(const float4*)(b1 + j);
    float z0 = acc.x + bb.x; z0 = z0 > 0.f ? z0 : a*z0;
    float z1 = acc.y + bb.y; z1 = z1 > 0.f ? z1 : a*z1;
    float z2 = acc.z + bb.z; z2 = z2 > 0.f ? z2 : a*z2;
    float z3 = acc.w + bb.w; z3 = z3 > 0.f ? z3 : a*z3;
    float s[8];
    #pragma unroll
    for (int o = 0; o < 8; o++)
        s[o] = z0*w2[(j+0)*8+o] + z1*w2[(j+1)*8+o] + z2*w2[(j+2)*8+o] + z3*w2[(j+3)*8+o];
    #pragma unroll
    for (int off = 32; off > 0; off >>= 1)
        #pragma unroll
        for (int o = 0; o < 8; o++) s[o] += __shfl_down(s[o], off);
    __shared__ float sred[5][8];
    if (lane == 0)
        for (int o = 0; o < 8; o++) sred[wid][o] = s[o];
    __syncthreads();
    if (t == 0) {
        float zo[8];
        for (int o = 0; o < 8; o++) {
            float z = sred[0][o]+sred[1][o]+sred[2][o]+sred[3][o]+sred[4][o] + b2[o];
            zo[o] = z > 0.f ? z : a*z;
        }
        float mn = zo[0];
        for (int o = 1; o < 8; o++) mn = fminf(mn, zo[o]);
        float v[8], mx = -3.402823e38f;
        for (int o = 0; o < 8; o++) { v[o] = zo[o] - mn; mx = fmaxf(mx, v[o]); }
        float sm = 0.f;
        for (int o = 0; o < 8; o++) { v[o] = v[o] / mx; sm += v[o]; }
        for (int o = 0; o < 8; o++) out[o] = v[o] / sm;
    }
}

// ---------------------------------------------------------------- launch
extern "C" void kernel_launch(void* const* d_in, const int* in_sizes, int n_in,
                              void* d_out, int out_size, void* d_ws, size_t ws_size,
                              hipStream_t stream) {
    const float* x      = (const float*)d_in[0];
    const int*   eidx   = (const int*)  d_in[1];
    const float* W1     = (const float*)d_in[2];
    const float* V1     = (const float*)d_in[3];
    const float* Ws     = (const float*)d_in[4];
    const float* Vs     = (const float*)d_in[5];
    const float* convb  = (const float*)d_in[6];
    const float* bng    = (const float*)d_in[7];
    const float* bnb    = (const float*)d_in[8];
    const float* bnm    = (const float*)d_in[9];
    const float* bnv    = (const float*)d_in[10];
    const float* poolp  = (const float*)d_in[11];
    const float* prelua = (const float*)d_in[12];
    const float* w1     = (const float*)d_in[13];
    const float* b1     = (const float*)d_in[14];
    const float* w2     = (const float*)d_in[15];
    const float* b2     = (const float*)d_in[16];
    float* out = (float*)d_out;

    float* wsf  = (float*)d_ws;
    float* H      = wsf;
    float* HW     = H     + (size_t)NMAX*128;
    float* AGG    = HW    + (size_t)NMAX*128;
    float* dinv   = AGG   + (size_t)NMAX*128;
    float* score  = dinv  + NMAX;
    float* rbuf   = score + NMAX;
    float* pnorm  = rbuf  + 2560;
    float* z1part = pnorm + 16;                  // LIN1B*1280
    unsigned* keys = (unsigned*)(z1part + LIN1B*1280);
    int* esrcA  = (int*)(keys + NMAX);
    int* edstA  = esrcA + NEDGE;
    int* erankA = edstA + NEDGE;
    int* esrcB  = erankA + NEDGE;
    int* edstB  = esrcB + NEDGE;
    int* erankB = edstB + NEDGE;
    int* csr    = erankB + NEDGE;
    int* degA   = csr   + NEDGE;
    int* degB   = degA  + NMAX;
    int* ghist  = degB  + NMAX;                  // GHN
    int* offs   = ghist + GHN;
    int* remap  = offs  + NMAX;
    int* keep_ids = remap + NMAX;
    int* lbsum  = keep_ids + NMAX;               // SB*2
    int* lbflag = lbsum + SB*2;                  // SB
    int* ecnt   = lbflag + SB;                   // 16
    int* selbuf = ecnt  + 16;                    // 16
    int* tkc    = selbuf + 16;                   // 64 (topk barrier counters, 5/layer)

    static const int NS[10] = {40000,32000,25600,20480,16384,13108,10487,8390,6712,5370};
    static const int KS[10] = {32000,25600,20480,16384,13108,10487,8390,6712,5370,4296};

    hipMemsetAsync(degA, 0, (size_t)NMAX*sizeof(int), stream);
    k_init<<<2500, 256, 0, stream>>>(eidx, esrcA, edstA, erankA, poolp, rbuf, pnorm,
                                     ecnt, degA, tkc);

    for (int i = 0; i < 10; i++) {
        int n = NS[i], k = KS[i];
        int chunk = (n + SB - 1) / SB;
        int* esrcP  = (i & 1) ? esrcB  : esrcA;
        int* edstP  = (i & 1) ? edstB  : edstA;
        int* erankP = (i & 1) ? erankB : erankA;
        int* esrcN  = (i & 1) ? esrcA  : esrcB;
        int* edstN  = (i & 1) ? edstA  : edstB;
        int* erankN = (i & 1) ? erankA : erankB;
        int* degP   = (i & 1) ? degB : degA;
        int* degN   = (i & 1) ? degA : degB;

        k_scan<<<SB, 256, 0, stream>>>(degP, offs, dinv, ghist, selbuf,
                                       lbsum, lbflag, n, chunk, i + 1);

        int gb = (i == 0) ? 0 : (n + GRB - 1) / GRB;
        k_fillgemm<<<FB + gb, 128, 0, stream>>>(esrcP, edstP, erankP, offs, csr, &ecnt[i],
                                                H, (i == 0) ? W1 : Ws + (size_t)(i-1)*16384,
                                                (i == 0) ? V1 : Vs + (size_t)(i-1)*16384,
                                                convb + i*128, HW, AGG, n);

        if (i == 0) {
            k_gather0<<<n, 128, 0, stream>>>(x, W1, V1, convb,
                                             bng, bnb, bnm, bnv, poolp, pnorm, prelua,
                                             offs, degP, dinv, csr, AGG, score, keys);
        } else {
            k_gather<<<n, 128, 0, stream>>>(HW, AGG, offs, degP, dinv, csr,
                                            bng, bnb, bnm, bnv, poolp, pnorm, prelua,
                                            score, keys, i);
        }

        k_topk<<<TKB, 1024, 0, stream>>>(keys, ghist, selbuf, degN,
                                         remap, keep_ids, tkc + i*5, n, k);

        k_pool<<<PBLK + EBLK, 256, 0, stream>>>(AGG, score, keep_ids, remap, H, rbuf,
                                                esrcP, edstP, esrcN, edstN, erankN,
                                                &ecnt[i], &ecnt[i+1], degN, k, i);
    }

    k_lin1<<<LIN1B, 320, 0, stream>>>(rbuf, w1, z1part);
    k_lin2<<<1, 320, 0, stream>>>(z1part, b1, w2, b2, prelua, out);
}

// Round 10
// 1413.609 us; speedup vs baseline: 1.1506x; 1.0210x over previous
//
#include <hip/hip_runtime.h>
#include <hip/hip_bf16.h>

#define NEDGE 640000
#define NMAX  40000
#define SB    40      // scan blocks
#define PBLK  256     // pool blocks
#define EBLK  320     // edge-compact blocks
#define FB    1280    // fill blocks (128 thr each)
#define LIN1B 64      // lin1 partial blocks
#define GRB   32      // gemm rows per block
#define KT    16      // gemm K-tile
#define TKB   32      // fused top-k blocks
#define GHN   5632    // global hist ints (2048+2048+1024+256+256)

// ---------------------------------------------------------------- helpers
__device__ inline void atomicMaxF(float* addr, float val) {
    unsigned* ua = (unsigned*)addr;
    unsigned old = *ua;
    while (__uint_as_float(old) < val) {
        unsigned assumed = old;
        old = atomicCAS(ua, assumed, __float_as_uint(val));
        if (old == assumed) break;
    }
}

__device__ inline unsigned orderKey(float s) {
    unsigned b = __float_as_uint(s);
    return (b & 0x80000000u) ? ~b : (b | 0x80000000u);
}

// ballot-dedup LDS histogram insert: O(1) atomics per distinct bin per wave
__device__ inline void histAdd(int* sh, int bin, bool act, int nbits) {
    unsigned long long mm = __ballot(act);
    for (int b = 0; b < nbits; b++) {
        unsigned long long bal = __ballot(act && ((bin >> b) & 1));
        mm &= ((bin >> b) & 1) ? bal : ~bal;
    }
    if (act) {
        int lane = threadIdx.x & 63;
        int leader = __ffsll(mm) - 1;
        if (lane == leader) atomicAdd(&sh[bin], __popcll(mm));
    }
}

// grid barrier for co-resident blocks (fresh counter per use, zeroed in k_init)
__device__ inline void gridbar(int* ctr, int target) {
    __syncthreads();
    if (threadIdx.x == 0) {
        __threadfence();
        __hip_atomic_fetch_add(ctr, 1, __ATOMIC_RELEASE, __HIP_MEMORY_SCOPE_AGENT);
        while (__hip_atomic_load(ctr, __ATOMIC_ACQUIRE, __HIP_MEMORY_SCOPE_AGENT) < target)
            __builtin_amdgcn_s_sleep(1);
        __threadfence();
    }
    __syncthreads();
}

__device__ inline void suffixSel2048(int* lh, const int* gh, int rem, int* outD, int* outR) {
    int t = threadIdx.x;
    lh[t] = gh[t]; lh[t+1024] = gh[t+1024];
    __syncthreads();
    for (int off = 1; off < 2048; off <<= 1) {
        int v0 = lh[t]      + ((t+off < 2048)      ? lh[t+off]      : 0);
        int v1 = lh[t+1024] + ((t+1024+off < 2048) ? lh[t+1024+off] : 0);
        __syncthreads();
        lh[t] = v0; lh[t+1024] = v1;
        __syncthreads();
    }
    for (int d = t; d < 2048; d += 1024) {
        int S = lh[d], Sn = (d == 2047) ? 0 : lh[d+1];
        if (S >= rem && Sn < rem) { *outD = d; *outR = rem - Sn; }
    }
    __syncthreads();
}

__device__ inline void suffixSel1024(int* lh, const int* gh, int rem, int* outD, int* outR) {
    int t = threadIdx.x;
    lh[t] = gh[t];
    __syncthreads();
    for (int off = 1; off < 1024; off <<= 1) {
        int v0 = lh[t] + ((t+off < 1024) ? lh[t+off] : 0);
        __syncthreads();
        lh[t] = v0;
        __syncthreads();
    }
    {
        int S = lh[t], Sn = (t == 1023) ? 0 : lh[t+1];
        if (S >= rem && Sn < rem) { *outD = t; *outR = rem - Sn; }
    }
    __syncthreads();
}

__device__ inline void prefixSel256(int* lh, const int* gh, int rem, int* outD, int* outR) {
    int t = threadIdx.x;
    if (t < 256) lh[t] = gh[t];
    __syncthreads();
    for (int off = 1; off < 256; off <<= 1) {
        int v = 0;
        if (t < 256) v = lh[t] + ((t >= off) ? lh[t-off] : 0);
        __syncthreads();
        if (t < 256) lh[t] = v;
        __syncthreads();
    }
    if (t < 256) {
        int P = lh[t], Pp = (t == 0) ? 0 : lh[t-1];
        if (P >= rem && Pp < rem) { *outD = t; *outR = rem - Pp; }
    }
    __syncthreads();
}

__device__ const float c_invk[10] = {
    1.0f/32000.0f, 1.0f/25600.0f, 1.0f/20480.0f, 1.0f/16384.0f, 1.0f/13108.0f,
    1.0f/10487.0f, 1.0f/8390.0f,  1.0f/6712.0f,  1.0f/5370.0f,  1.0f/4296.0f };

// ---------------------------------------------------------------- init (+ layer-0 degree count + ranks)
__global__ void k_init(const int* __restrict__ eidx, int* __restrict__ esrc,
                       int* __restrict__ edst, int* __restrict__ erank,
                       const float* __restrict__ poolp,
                       float* __restrict__ rbuf, float* __restrict__ pnorm,
                       int* __restrict__ ecnt, int* __restrict__ degA,
                       int* __restrict__ tkc) {
    int b = blockIdx.x, t = threadIdx.x;
    if (b < 10) {
        rbuf[b*256 + t] = (t < 128) ? -3.402823e38f : 0.0f;
        __shared__ float red[256];
        float v = 0.0f;
        if (t < 128) { float pv = poolp[b*128 + t]; v = pv*pv; }
        red[t] = v; __syncthreads();
        for (int s = 128; s > 0; s >>= 1) { if (t < s) red[t] += red[t+s]; __syncthreads(); }
        if (t == 0) pnorm[b] = sqrtf(red[0]);
    }
    if (b == 10 && t < 16) ecnt[t] = (t == 0) ? NEDGE : 0;
    if (b == 11 && t < 64) tkc[t] = 0;
    int e = b*256 + t;
    if (e < NEDGE) {
        int d = eidx[NEDGE + e];
        esrc[e] = eidx[e]; edst[e] = d;
        erank[e] = atomicAdd(&degA[d], 1);
    }
}

// ---------------------------------------------------------------- fused single-pass scan (decoupled lookback)
__global__ void k_scan(const int* __restrict__ deg,
                       int* __restrict__ offs, float* __restrict__ dinv,
                       int* __restrict__ ghist, int* __restrict__ selbuf,
                       int* __restrict__ lbsum, int* __restrict__ lbflag,
                       int n, int chunk, int epoch) {
    int b = blockIdx.x, t = threadIdx.x, lane = t & 63, wid = t >> 6;
    __shared__ int red[256];
    __shared__ int s_excl;
    __shared__ int wsum[4];
    __shared__ int s_carry;
    if (b == 0) {
        for (int jj = t; jj < GHN; jj += 256) ghist[jj] = 0;
        if (t == 0) { selbuf[2] = 0; selbuf[5] = 0; }
    }
    int start = b*chunk, end = min(start + chunk, n);
    int s = 0;
    for (int i = start + t; i < end; i += 256) s += deg[i];
    red[t] = s; __syncthreads();
    for (int st = 128; st > 0; st >>= 1) { if (t < st) red[t] += red[t+st]; __syncthreads(); }
    if (t == 0) {
        int total = red[0];
        int e1 = epoch*4 + 1, e2 = epoch*4 + 2;
        __hip_atomic_store(&lbsum[b*2], total, __ATOMIC_RELAXED, __HIP_MEMORY_SCOPE_AGENT);
        __hip_atomic_store(&lbflag[b], e1, __ATOMIC_RELEASE, __HIP_MEMORY_SCOPE_AGENT);
        int excl = 0;
        for (int p = b - 1; p >= 0; ) {
            int f;
            do { f = __hip_atomic_load(&lbflag[p], __ATOMIC_ACQUIRE, __HIP_MEMORY_SCOPE_AGENT); }
            while (f != e1 && f != e2);
            if (f == e2) { excl += __hip_atomic_load(&lbsum[p*2+1], __ATOMIC_RELAXED, __HIP_MEMORY_SCOPE_AGENT); break; }
            excl += __hip_atomic_load(&lbsum[p*2], __ATOMIC_RELAXED, __HIP_MEMORY_SCOPE_AGENT);
            p--;
        }
        __hip_atomic_store(&lbsum[b*2+1], excl + total, __ATOMIC_RELAXED, __HIP_MEMORY_SCOPE_AGENT);
        __hip_atomic_store(&lbflag[b], e2, __ATOMIC_RELEASE, __HIP_MEMORY_SCOPE_AGENT);
        s_excl = excl;
    }
    __syncthreads();
    if (t == 0) s_carry = s_excl;
    __syncthreads();
    for (int base = start; base < end; base += 256) {
        int i = base + t;
        int d = (i < end) ? deg[i] : 0;
        int incl = d;
        for (int off = 1; off < 64; off <<= 1) {
            int o = __shfl_up(incl, off);
            if (lane >= off) incl += o;
        }
        if (lane == 63) wsum[wid] = incl;
        __syncthreads();
        if (t == 0) { int c = s_carry; for (int w = 0; w < 4; w++) { int tmp = wsum[w]; wsum[w] = c; c += tmp; } s_carry = c; }
        __syncthreads();
        int p = wsum[wid] + incl - d;
        if (i < end) {
            offs[i] = p;
            dinv[i] = (d > 0) ? 1.0f/sqrtf((float)d) : 0.0f;
        }
        __syncthreads();
    }
}

// ---------------------------------------------------------------- fused CSR fill + GEMM (h staged via keep_ids gather)
__global__ __launch_bounds__(128) void k_fillgemm(const int* __restrict__ esrc, const int* __restrict__ edst,
        const int* __restrict__ erank, const int* __restrict__ offs,
        int* __restrict__ csr, const int* __restrict__ ecnt,
        const float* __restrict__ hsrc, const int* __restrict__ keep_ids,
        const float* __restrict__ score,
        const float* __restrict__ W, const float* __restrict__ V,
        const float* __restrict__ bias, float* __restrict__ HW, float* __restrict__ AGG, int n) {
    int b = blockIdx.x, t = threadIdx.x;
    if (b < FB) {
        int ec = *ecnt;
        for (int e = b*128 + t; e < ec; e += FB*128) {
            csr[offs[edst[e]] + erank[e]] = esrc[e];
        }
        return;
    }
    __shared__ __align__(16) float ht[128*36];
    __shared__ __align__(16) float wt[KT*128];
    __shared__ __align__(16) float vt[KT*128];
    int v0 = (b - FB) * GRB;
    for (int it = 0; it < GRB; it++) {
        int r = min(v0 + it, n - 1);
        int vv = keep_ids[r];
        float sc = score[vv];
        ht[t*36 + it] = hsrc[(size_t)vv*128 + t] * sc;
    }
    float accW[GRB], accV[GRB];
    #pragma unroll
    for (int r = 0; r < GRB; r++) { accW[r] = 0.0f; accV[r] = 0.0f; }
    for (int k0 = 0; k0 < 128; k0 += KT) {
        __syncthreads();
        const float4* Wp = (const float4*)(W + k0*128);
        const float4* Vp = (const float4*)(V + k0*128);
        float4* w4 = (float4*)wt;
        float4* v4 = (float4*)vt;
        #pragma unroll
        for (int q = 0; q < 4; q++) { w4[q*128 + t] = Wp[q*128 + t]; v4[q*128 + t] = Vp[q*128 + t]; }
        __syncthreads();
        for (int kk = 0; kk < KT; kk++) {
            float mw = wt[kk*128 + t];
            float mv = vt[kk*128 + t];
            const float* hp = &ht[(k0 + kk)*36];
            #pragma unroll
            for (int r4 = 0; r4 < GRB; r4 += 4) {
                float4 hq = *(const float4*)(hp + r4);
                accW[r4+0] += hq.x*mw;  accV[r4+0] += hq.x*mv;
                accW[r4+1] += hq.y*mw;  accV[r4+1] += hq.y*mv;
                accW[r4+2] += hq.z*mw;  accV[r4+2] += hq.z*mv;
                accW[r4+3] += hq.w*mw;  accV[r4+3] += hq.w*mv;
            }
        }
    }
    float bb = bias[t];
    for (int r = 0; r < GRB; r++) {
        int v = v0 + r;
        if (v >= n) break;
        HW[v*128 + t]  = accW[r];
        AGG[v*128 + t] = accV[r] + bb;
    }
}

// ---------------------------------------------------------------- layer-0 fused node update
__global__ __launch_bounds__(128) void k_gather0(
    const float* __restrict__ x, const float* __restrict__ W1, const float* __restrict__ V1,
    const float* __restrict__ convb,
    const float* __restrict__ bng, const float* __restrict__ bnb,
    const float* __restrict__ bnm, const float* __restrict__ bnv,
    const float* __restrict__ poolp, const float* __restrict__ pnorm,
    const float* __restrict__ prelua,
    const int* __restrict__ offs, const int* __restrict__ deg, const float* __restrict__ dinv,
    const int* __restrict__ csr,
    float* __restrict__ AGG, float* __restrict__ score, unsigned* __restrict__ keys) {
    int v = blockIdx.x, j = threadIdx.x;
    __shared__ float red[128];
    int off = offs[v], dg = deg[v];
    float accs = 0.0f;
    for (int c = j; c < dg; c += 128) { int s = csr[off + c]; accs += x[s]*dinv[s]; }
    red[j] = accs; __syncthreads();
    for (int st = 64; st > 0; st >>= 1) { if (j < st) red[j] += red[j+st]; __syncthreads(); }
    float aggs = red[0] * dinv[v];
    __syncthreads();
    float h2 = aggs*W1[j] + x[v]*V1[j] + convb[j];
    h2 = fmaxf(h2, 0.0f);
    float scale = bng[j] / sqrtf(bnv[j] + 1e-5f);
    h2 = (h2 - bnm[j])*scale + bnb[j];
    float a = prelua[0];
    h2 = (h2 > 0.0f) ? h2 : a*h2;
    AGG[v*128 + j] = h2;
    red[j] = h2 * poolp[j]; __syncthreads();
    for (int st = 64; st > 0; st >>= 1) { if (j < st) red[j] += red[j+st]; __syncthreads(); }
    if (j == 0) {
        float sc = tanhf(red[0] / pnorm[0]);
        score[v] = sc;
        keys[v]  = orderKey(sc);
    }
}

// ---------------------------------------------------------------- generic fused gather + update + score
__global__ __launch_bounds__(128) void k_gather(
    const float* __restrict__ HW, float* __restrict__ AGG,
    const int* __restrict__ offs, const int* __restrict__ deg, const float* __restrict__ dinv,
    const int* __restrict__ csr,
    const float* __restrict__ bng, const float* __restrict__ bnb,
    const float* __restrict__ bnm, const float* __restrict__ bnv,
    const float* __restrict__ poolp, const float* __restrict__ pnorm,
    const float* __restrict__ prelua,
    float* __restrict__ score, unsigned* __restrict__ keys, int layer) {
    int v = blockIdx.x, j = threadIdx.x;
    __shared__ int   s_src[128];
    __shared__ float s_dv[128];
    __shared__ float red[128];
    int off = offs[v], dg = deg[v];
    float acc = 0.0f;
    for (int base = 0; base < dg; base += 128) {
        int cnt = min(128, dg - base);
        if (j < cnt) { int s = csr[off + base + j]; s_src[j] = s; s_dv[j] = dinv[s]; }
        __syncthreads();
        for (int c = 0; c < cnt; c++) acc += HW[s_src[c]*128 + j] * s_dv[c];
        __syncthreads();
    }
    int gj = layer*128 + j;
    float h2 = AGG[v*128 + j] + acc*dinv[v];
    h2 = fmaxf(h2, 0.0f);
    float scale = bng[gj] / sqrtf(bnv[gj] + 1e-5f);
    h2 = (h2 - bnm[gj])*scale + bnb[gj];
    float a = prelua[0];
    h2 = (h2 > 0.0f) ? h2 : a*h2;
    AGG[v*128 + j] = h2;
    red[j] = h2 * poolp[gj]; __syncthreads();
    for (int st = 64; st > 0; st >>= 1) { if (j < st) red[j] += red[j+st]; __syncthreads(); }
    if (j == 0) {
        float sc = tanhf(red[0] / pnorm[layer]);
        score[v] = sc;
        keys[v]  = orderKey(sc);
    }
}

// ---------------------------------------------------------------- fused top-k, all phases grid-parallel
__global__ __launch_bounds__(1024) void k_topk(const unsigned* __restrict__ keys,
                                               int* __restrict__ gh, int* __restrict__ selbuf,
                                               int* __restrict__ degN,
                                               int* __restrict__ remap, int* __restrict__ keep_ids,
                                               int* __restrict__ bar, int n, int kk) {
    __shared__ int lh[2048];
    __shared__ int s_d1, s_r1, s_dA, s_rA, s_dB, s_ntk, s_bC, s_r2, s_lowD, s_lowR;
    __shared__ int s_base, s_cur;
    int t = threadIdx.x, b = blockIdx.x, lane = t & 63;
    int* h1 = gh;
    int* h2 = gh + 2048;
    int* h3 = gh + 4096;
    int* h4 = gh + 5120;
    int* h5 = gh + 5376;

    for (int i = b*1024 + t; i < NMAX; i += TKB*1024) degN[i] = 0;

    int nR = (n + 1023) & ~1023;
    lh[t] = 0; lh[t+1024] = 0;
    __syncthreads();
    for (int i = b*1024 + t; i < nR; i += TKB*1024) {
        bool act = (i < n);
        int bin = act ? (int)(keys[i] >> 21) : 0;
        histAdd(lh, bin, act, 11);
    }
    __syncthreads();
    { int c = lh[t]; if (c) atomicAdd(&h1[t], c); c = lh[t+1024]; if (c) atomicAdd(&h1[t+1024], c); }
    gridbar(&bar[0], TKB);
    suffixSel2048(lh, h1, kk, &s_d1, &s_r1);
    int bstar = s_d1;

    lh[t] = 0; lh[t+1024] = 0;
    __syncthreads();
    for (int i = b*1024 + t; i < nR; i += TKB*1024) {
        bool act = false; int bin = 0;
        if (i < n) { unsigned key = keys[i]; act = ((int)(key >> 21) == bstar); bin = (int)((key >> 10) & 2047); }
        histAdd(lh, act ? bin : 0, act, 11);
    }
    __syncthreads();
    { int c = lh[t]; if (c) atomicAdd(&h2[t], c); c = lh[t+1024]; if (c) atomicAdd(&h2[t+1024], c); }
    gridbar(&bar[1], TKB);
    suffixSel2048(lh, h2, s_r1, &s_dA, &s_rA);
    unsigned top21 = ((unsigned)bstar << 11) | (unsigned)s_dA;

    lh[t] = 0;
    __syncthreads();
    for (int i = b*1024 + t; i < nR; i += TKB*1024) {
        bool act = false; int bin = 0;
        if (i < n) { unsigned key = keys[i]; act = ((key >> 10) == top21); bin = (int)(key & 1023); }
        histAdd(lh, act ? bin : 0, act, 10);
    }
    __syncthreads();
    { int c = lh[t]; if (c) atomicAdd(&h3[t], c); }
    gridbar(&bar[2], TKB);
    suffixSel1024(lh, h3, s_rA, &s_dB, &s_ntk);
    unsigned thresh = (top21 << 10) | (unsigned)s_dB;

    if (t < 256) lh[t] = 0;
    __syncthreads();
    for (int i = b*1024 + t; i < n; i += TKB*1024)
        if (keys[i] == thresh) atomicAdd(&lh[i >> 8], 1);
    __syncthreads();
    if (t < 256) { int c = lh[t]; if (c) atomicAdd(&h4[t], c); }
    gridbar(&bar[3], TKB);
    prefixSel256(lh, h4, s_ntk, &s_bC, &s_r2);
    int bC = s_bC;

    if (t < 256) lh[t] = 0;
    __syncthreads();
    for (int i = b*1024 + t; i < n; i += TKB*1024)
        if (keys[i] == thresh && (i >> 8) == bC) atomicAdd(&lh[i & 255], 1);
    __syncthreads();
    if (t < 256) { int c = lh[t]; if (c) atomicAdd(&h5[t], c); }
    gridbar(&bar[4], TKB);
    prefixSel256(lh, h5, s_r2, &s_lowD, &s_lowR);
    int cut = (bC << 8) | s_lowD;

    {
        int cnt = 0;
        for (int base = b*1024; base < n; base += TKB*1024) {
            int i = base + t;
            if (i < n) {
                unsigned key = keys[i];
                cnt += (key > thresh) || (key == thresh && i <= cut);
            }
        }
        lh[t] = cnt; __syncthreads();
        for (int st = 512; st > 0; st >>= 1) { if (t < st) lh[t] += lh[t+st]; __syncthreads(); }
        if (t == 0) { s_base = atomicAdd(&selbuf[5], lh[0]); s_cur = 0; }
        __syncthreads();
        for (int base = b*1024; base < n; base += TKB*1024) {
            int i = base + t;
            bool keep = false;
            if (i < n) {
                unsigned key = keys[i];
                keep = (key > thresh) || (key == thresh && i <= cut);
            }
            unsigned long long m = __ballot(keep);
            int wcnt = __popcll(m);
            int wbase = 0;
            if (lane == 0 && wcnt) wbase = atomicAdd(&s_cur, wcnt);
            wbase = __shfl(wbase, 0);
            if (keep) {
                int slot = s_base + wbase + __popcll(m & ((1ULL << lane) - 1));
                remap[i] = slot; keep_ids[slot] = i;
            } else if (i < n) remap[i] = -1;
        }
    }
}

// ---------------------------------------------------------------- pool (read-only max/mean) + edge remap/compact
__global__ void k_pool(const float* __restrict__ AGG, const float* __restrict__ score,
                       const int* __restrict__ keep_ids, const int* __restrict__ remap,
                       float* __restrict__ rbuf,
                       const int* __restrict__ esrcP, const int* __restrict__ edstP,
                       int* __restrict__ esrcN, int* __restrict__ edstN, int* __restrict__ erankN,
                       const int* __restrict__ ecntP, int* __restrict__ ecntN,
                       int* __restrict__ degN, int k, int layer) {
    int b = blockIdx.x, t = threadIdx.x;
    if (b < PBLK) {
        int sub = t >> 5, c = t & 31;        // 8 row-streams/block, float4 channels
        float4 mx = make_float4(-3.402823e38f, -3.402823e38f, -3.402823e38f, -3.402823e38f);
        float4 sm = make_float4(0.f, 0.f, 0.f, 0.f);
        int s = b*8 + sub;
        int v = (s < k) ? keep_ids[s] : 0;
        while (s < k) {
            float sc = score[v];
            float4 val = *(const float4*)(AGG + (size_t)v*128 + c*4);
            int s2 = s + PBLK*8;
            int v2 = (s2 < k) ? keep_ids[s2] : 0;   // prefetch next row id
            val.x *= sc; val.y *= sc; val.z *= sc; val.w *= sc;
            mx.x = fmaxf(mx.x, val.x); mx.y = fmaxf(mx.y, val.y);
            mx.z = fmaxf(mx.z, val.z); mx.w = fmaxf(mx.w, val.w);
            sm.x += val.x; sm.y += val.y; sm.z += val.z; sm.w += val.w;
            s = s2; v = v2;
        }
        __shared__ float shm[8][132], shs[8][132];
        *(float4*)&shm[sub][c*4] = mx;
        *(float4*)&shs[sub][c*4] = sm;
        __syncthreads();
        if (t < 128) {
            float m = shm[0][t], su = shs[0][t];
            #pragma unroll
            for (int q = 1; q < 8; q++) { m = fmaxf(m, shm[q][t]); su += shs[q][t]; }
            atomicMaxF(&rbuf[layer*256 + t], m);
            atomicAdd(&rbuf[layer*256 + 128 + t], su);
        }
    } else {
        int eb = b - PBLK, lane = t & 63;
        int ec = *ecntP;
        __shared__ int s_base, s_cur;
        __shared__ int red[256];
        int cnt = 0;
        for (int base = eb*256; base < ec; base += EBLK*256) {
            int e = base + t;
            if (e < ec) {
                int ns = remap[esrcP[e]], nd = remap[edstP[e]];
                cnt += (ns >= 0 && nd >= 0);
            }
        }
        red[t] = cnt; __syncthreads();
        for (int st = 128; st > 0; st >>= 1) { if (t < st) red[t] += red[t+st]; __syncthreads(); }
        if (t == 0) { s_base = atomicAdd(ecntN, red[0]); s_cur = 0; }
        __syncthreads();
        for (int base = eb*256; base < ec; base += EBLK*256) {
            int e = base + t;
            bool keep = false; int ns = 0, nd = 0;
            if (e < ec) {
                ns = remap[esrcP[e]]; nd = remap[edstP[e]];
                keep = (ns >= 0 && nd >= 0);
            }
            unsigned long long m = __ballot(keep);
            int wcnt = __popcll(m);
            int wbase = 0;
            if (lane == 0 && wcnt) wbase = atomicAdd(&s_cur, wcnt);
            wbase = __shfl(wbase, 0);
            if (keep) {
                int pos = s_base + wbase + __popcll(m & ((1ULL << lane) - 1));
                esrcN[pos] = ns; edstN[pos] = nd;
                erankN[pos] = atomicAdd(&degN[nd], 1);
            }
        }
    }
}

// ---------------------------------------------------------------- MLP head
__global__ __launch_bounds__(320) void k_lin1(const float* __restrict__ rbuf,
                                              const float* __restrict__ w1,
                                              float* __restrict__ z1part) {
    int b = blockIdx.x, t = threadIdx.x;
    int j = t*4;
    float4 acc = make_float4(0.f, 0.f, 0.f, 0.f);
    int i0 = b*40;
    for (int r = 0; r < 40; r++) {
        int i = i0 + r;
        float rv = rbuf[i];
        if (i & 128) rv *= c_invk[i >> 8];
        float4 w = *(const float4*)(w1 + (size_t)i*1280 + j);
        acc.x += rv*w.x; acc.y += rv*w.y; acc.z += rv*w.z; acc.w += rv*w.w;
    }
    *(float4*)(z1part + b*1280 + j) = acc;
}

__global__ __launch_bounds__(320) void k_lin2(const float* __restrict__ z1part,
                                              const float* __restrict__ b1,
                                              const float* __restrict__ w2, const float* __restrict__ b2,
                                              const float* __restrict__ prelua, float* __restrict__ out) {
    int t = threadIdx.x, lane = t & 63, wid = t >> 6;
    float a = prelua[0];
    int j = t*4;
    float4 acc = make_float4(0.f, 0.f, 0.f, 0.f);
    for (int p = 0; p < LIN1B; p++) {
        float4 v = *(const float4*)(z1part + p*1280 + j);
        acc.x += v.x; acc.y += v.y; acc.z += v.z; acc.w += v.w;
    }
    float4 bb = *(const float4*)(b1 + j);
    float z0 = acc.x + bb.x; z0 = z0 > 0.f ? z0 : a*z0;
    float z1 = acc.y + bb.y; z1 = z1 > 0.f ? z1 : a*z1;
    float z2 = acc.z + bb.z; z2 = z2 > 0.f ? z2 : a*z2;
    float z3 = acc.w + bb.w; z3 = z3 > 0.f ? z3 : a*z3;
    float s[8];
    #pragma unroll
    for (int o = 0; o < 8; o++)
        s[o] = z0*w2[(j+0)*8+o] + z1*w2[(j+1)*8+o] + z2*w2[(j+2)*8+o] + z3*w2[(j+3)*8+o];
    #pragma unroll
    for (int off = 32; off > 0; off >>= 1)
        #pragma unroll
        for (int o = 0; o < 8; o++) s[o] += __shfl_down(s[o], off);
    __shared__ float sred[5][8];
    if (lane == 0)
        for (int o = 0; o < 8; o++) sred[wid][o] = s[o];
    __syncthreads();
    if (t == 0) {
        float zo[8];
        for (int o = 0; o < 8; o++) {
            float z = sred[0][o]+sred[1][o]+sred[2][o]+sred[3][o]+sred[4][o] + b2[o];
            zo[o] = z > 0.f ? z : a*z;
        }
        float mn = zo[0];
        for (int o = 1; o < 8; o++) mn = fminf(mn, zo[o]);
        float v[8], mx = -3.402823e38f;
        for (int o = 0; o < 8; o++) { v[o] = zo[o] - mn; mx = fmaxf(mx, v[o]); }
        float sm = 0.f;
        for (int o = 0; o < 8; o++) { v[o] = v[o] / mx; sm += v[o]; }
        for (int o = 0; o < 8; o++) out[o] = v[o] / sm;
    }
}

// ---------------------------------------------------------------- launch
extern "C" void kernel_launch(void* const* d_in, const int* in_sizes, int n_in,
                              void* d_out, int out_size, void* d_ws, size_t ws_size,
                              hipStream_t stream) {
    const float* x      = (const float*)d_in[0];
    const int*   eidx   = (const int*)  d_in[1];
    const float* W1     = (const float*)d_in[2];
    const float* V1     = (const float*)d_in[3];
    const float* Ws     = (const float*)d_in[4];
    const float* Vs     = (const float*)d_in[5];
    const float* convb  = (const float*)d_in[6];
    const float* bng    = (const float*)d_in[7];
    const float* bnb    = (const float*)d_in[8];
    const float* bnm    = (const float*)d_in[9];
    const float* bnv    = (const float*)d_in[10];
    const float* poolp  = (const float*)d_in[11];
    const float* prelua = (const float*)d_in[12];
    const float* w1     = (const float*)d_in[13];
    const float* b1     = (const float*)d_in[14];
    const float* w2     = (const float*)d_in[15];
    const float* b2     = (const float*)d_in[16];
    float* out = (float*)d_out;

    float* wsf  = (float*)d_ws;
    float* aggA   = wsf;                          // NMAX*128
    float* aggB   = aggA  + (size_t)NMAX*128;     // NMAX*128
    float* HW     = aggB  + (size_t)NMAX*128;     // NMAX*128
    float* dinv   = HW    + (size_t)NMAX*128;
    float* score  = dinv  + NMAX;
    float* rbuf   = score + NMAX;
    float* pnorm  = rbuf  + 2560;
    float* z1part = pnorm + 16;                   // LIN1B*1280
    unsigned* keys = (unsigned*)(z1part + LIN1B*1280);
    int* esrcA  = (int*)(keys + NMAX);
    int* edstA  = esrcA + NEDGE;
    int* erankA = edstA + NEDGE;
    int* esrcB  = erankA + NEDGE;
    int* edstB  = esrcB + NEDGE;
    int* erankB = edstB + NEDGE;
    int* csr    = erankB + NEDGE;
    int* degA   = csr   + NEDGE;
    int* degB   = degA  + NMAX;
    int* ghist  = degB  + NMAX;                   // GHN
    int* offs   = ghist + GHN;
    int* remap  = offs  + NMAX;
    int* keep_ids = remap + NMAX;
    int* lbsum  = keep_ids + NMAX;                // SB*2
    int* lbflag = lbsum + SB*2;                   // SB
    int* ecnt   = lbflag + SB;                    // 16
    int* selbuf = ecnt  + 16;                     // 16
    int* tkc    = selbuf + 16;                    // 64

    static const int NS[10] = {40000,32000,25600,20480,16384,13108,10487,8390,6712,5370};
    static const int KS[10] = {32000,25600,20480,16384,13108,10487,8390,6712,5370,4296};

    hipMemsetAsync(degA, 0, (size_t)NMAX*sizeof(int), stream);
    k_init<<<2500, 256, 0, stream>>>(eidx, esrcA, edstA, erankA, poolp, rbuf, pnorm,
                                     ecnt, degA, tkc);

    for (int i = 0; i < 10; i++) {
        int n = NS[i], k = KS[i];
        int chunk = (n + SB - 1) / SB;
        int* esrcP  = (i & 1) ? esrcB  : esrcA;
        int* edstP  = (i & 1) ? edstB  : edstA;
        int* erankP = (i & 1) ? erankB : erankA;
        int* esrcN  = (i & 1) ? esrcA  : esrcB;
        int* edstN  = (i & 1) ? edstA  : edstB;
        int* erankN = (i & 1) ? erankA : erankB;
        int* degP   = (i & 1) ? degB : degA;
        int* degN   = (i & 1) ? degA : degB;
        float* AGGc = (i & 1) ? aggB : aggA;      // current layer features
        float* AGGp = (i & 1) ? aggA : aggB;      // previous layer features

        k_scan<<<SB, 256, 0, stream>>>(degP, offs, dinv, ghist, selbuf,
                                       lbsum, lbflag, n, chunk, i + 1);

        int gb = (i == 0) ? 0 : (n + GRB - 1) / GRB;
        k_fillgemm<<<FB + gb, 128, 0, stream>>>(esrcP, edstP, erankP, offs, csr, &ecnt[i],
                                                AGGp, keep_ids, score,
                                                (i == 0) ? W1 : Ws + (size_t)(i-1)*16384,
                                                (i == 0) ? V1 : Vs + (size_t)(i-1)*16384,
                                                convb + i*128, HW, AGGc, n);

        if (i == 0) {
            k_gather0<<<n, 128, 0, stream>>>(x, W1, V1, convb,
                                             bng, bnb, bnm, bnv, poolp, pnorm, prelua,
                                             offs, degP, dinv, csr, AGGc, score, keys);
        } else {
            k_gather<<<n, 128, 0, stream>>>(HW, AGGc, offs, degP, dinv, csr,
                                            bng, bnb, bnm, bnv, poolp, pnorm, prelua,
                                            score, keys, i);
        }

        k_topk<<<TKB, 1024, 0, stream>>>(keys, ghist, selbuf, degN,
                                         remap, keep_ids, tkc + i*5, n, k);

        k_pool<<<PBLK + EBLK, 256, 0, stream>>>(AGGc, score, keep_ids, remap, rbuf,
                                                esrcP, edstP, esrcN, edstN, erankN,
                                                &ecnt[i], &ecnt[i+1], degN, k, i);
    }

    k_lin1<<<LIN1B, 320, 0, stream>>>(rbuf, w1, z1part);
    k_lin2<<<1, 320, 0, stream>>>(z1part, b1, w2, b2, prelua, out);
}

// Round 11
// 1261.659 us; speedup vs baseline: 1.2891x; 1.1204x over previous
//
#include <hip/hip_runtime.h>
#include <hip/hip_bf16.h>

#define NEDGE 640000
#define NMAX  40000
#define SB    40      // scan blocks
#define RB    16      // pool-scratch reduce blocks
#define EBLK  512     // edge-compact blocks (128 thr)
#define FB    1280    // fill blocks (128 thr each)
#define LIN1B 64      // lin1 partial blocks
#define GRB   32      // gemm rows per block
#define TKB   32      // fused top-k blocks
#define GHN   5632    // global hist ints (2048+2048+1024+256+256)
#define GBMAX 1024    // max gemm blocks per layer (<= ceil(32000/32)=1000)

// ---------------------------------------------------------------- helpers
__device__ inline unsigned orderKey(float s) {
    unsigned b = __float_as_uint(s);
    return (b & 0x80000000u) ? ~b : (b | 0x80000000u);
}

// ballot-dedup LDS histogram insert: O(1) atomics per distinct bin per wave
__device__ inline void histAdd(int* sh, int bin, bool act, int nbits) {
    unsigned long long mm = __ballot(act);
    for (int b = 0; b < nbits; b++) {
        unsigned long long bal = __ballot(act && ((bin >> b) & 1));
        mm &= ((bin >> b) & 1) ? bal : ~bal;
    }
    if (act) {
        int lane = threadIdx.x & 63;
        int leader = __ffsll(mm) - 1;
        if (lane == leader) atomicAdd(&sh[bin], __popcll(mm));
    }
}

// grid barrier for co-resident blocks (fresh counter per use, zeroed in k_init)
__device__ inline void gridbar(int* ctr, int target) {
    __syncthreads();
    if (threadIdx.x == 0) {
        __threadfence();
        __hip_atomic_fetch_add(ctr, 1, __ATOMIC_RELEASE, __HIP_MEMORY_SCOPE_AGENT);
        while (__hip_atomic_load(ctr, __ATOMIC_ACQUIRE, __HIP_MEMORY_SCOPE_AGENT) < target)
            __builtin_amdgcn_s_sleep(1);
        __threadfence();
    }
    __syncthreads();
}

__device__ inline void suffixSel2048(int* lh, const int* gh, int rem, int* outD, int* outR) {
    int t = threadIdx.x;
    lh[t] = gh[t]; lh[t+1024] = gh[t+1024];
    __syncthreads();
    for (int off = 1; off < 2048; off <<= 1) {
        int v0 = lh[t]      + ((t+off < 2048)      ? lh[t+off]      : 0);
        int v1 = lh[t+1024] + ((t+1024+off < 2048) ? lh[t+1024+off] : 0);
        __syncthreads();
        lh[t] = v0; lh[t+1024] = v1;
        __syncthreads();
    }
    for (int d = t; d < 2048; d += 1024) {
        int S = lh[d], Sn = (d == 2047) ? 0 : lh[d+1];
        if (S >= rem && Sn < rem) { *outD = d; *outR = rem - Sn; }
    }
    __syncthreads();
}

__device__ inline void suffixSel1024(int* lh, const int* gh, int rem, int* outD, int* outR) {
    int t = threadIdx.x;
    lh[t] = gh[t];
    __syncthreads();
    for (int off = 1; off < 1024; off <<= 1) {
        int v0 = lh[t] + ((t+off < 1024) ? lh[t+off] : 0);
        __syncthreads();
        lh[t] = v0;
        __syncthreads();
    }
    {
        int S = lh[t], Sn = (t == 1023) ? 0 : lh[t+1];
        if (S >= rem && Sn < rem) { *outD = t; *outR = rem - Sn; }
    }
    __syncthreads();
}

__device__ inline void prefixSel256(int* lh, const int* gh, int rem, int* outD, int* outR) {
    int t = threadIdx.x;
    if (t < 256) lh[t] = gh[t];
    __syncthreads();
    for (int off = 1; off < 256; off <<= 1) {
        int v = 0;
        if (t < 256) v = lh[t] + ((t >= off) ? lh[t-off] : 0);
        __syncthreads();
        if (t < 256) lh[t] = v;
        __syncthreads();
    }
    if (t < 256) {
        int P = lh[t], Pp = (t == 0) ? 0 : lh[t-1];
        if (P >= rem && Pp < rem) { *outD = t; *outR = rem - Pp; }
    }
    __syncthreads();
}

// reduce pool-stat scratch (gbP blocks x 256) -> rbuf[L*256 .. +256), 16 blocks x 256 thr
__device__ inline void poolReduce(const float* __restrict__ scr, float* __restrict__ rbuf,
                                  int gbP, int L, int rblk) {
    int t = threadIdx.x;
    int ch = rblk*16 + (t >> 4);
    int l16 = t & 15;
    bool isMax = ch < 128;
    float acc = isMax ? -3.402823e38f : 0.f;
    for (int r = l16; r < gbP; r += 16) {
        float v = scr[r*256 + ch];
        acc = isMax ? fmaxf(acc, v) : (acc + v);
    }
    __shared__ float sred[16][17];
    sred[t >> 4][l16] = acc;
    __syncthreads();
    if (l16 == 0) {
        float a = sred[t >> 4][0];
        for (int q = 1; q < 16; q++) {
            float v = sred[t >> 4][q];
            a = isMax ? fmaxf(a, v) : (a + v);
        }
        rbuf[L*256 + ch] = a;
    }
}

__device__ const float c_invk[10] = {
    1.0f/32000.0f, 1.0f/25600.0f, 1.0f/20480.0f, 1.0f/16384.0f, 1.0f/13108.0f,
    1.0f/10487.0f, 1.0f/8390.0f,  1.0f/6712.0f,  1.0f/5370.0f,  1.0f/4296.0f };

// ---------------------------------------------------------------- init (+ layer-0 degree count + ranks)
__global__ void k_init(const int* __restrict__ eidx, int* __restrict__ esrc,
                       int* __restrict__ edst, int* __restrict__ erank,
                       const float* __restrict__ poolp,
                       float* __restrict__ rbuf, float* __restrict__ pnorm,
                       int* __restrict__ ecnt, int* __restrict__ degA,
                       int* __restrict__ tkc) {
    int b = blockIdx.x, t = threadIdx.x;
    if (b < 10) {
        rbuf[b*256 + t] = (t < 128) ? -3.402823e38f : 0.0f;
        __shared__ float red[256];
        float v = 0.0f;
        if (t < 128) { float pv = poolp[b*128 + t]; v = pv*pv; }
        red[t] = v; __syncthreads();
        for (int s = 128; s > 0; s >>= 1) { if (t < s) red[t] += red[t+s]; __syncthreads(); }
        if (t == 0) pnorm[b] = sqrtf(red[0]);
    }
    if (b == 10 && t < 16) ecnt[t] = (t == 0) ? NEDGE : 0;
    if (b == 11 && t < 64) tkc[t] = 0;
    int e = b*256 + t;
    if (e < NEDGE) {
        int d = eidx[NEDGE + e];
        esrc[e] = eidx[e]; edst[e] = d;
        erank[e] = atomicAdd(&degA[d], 1);
    }
}

// ---------------------------------------------------------------- fused single-pass scan (decoupled lookback)
// blocks [0,SB): scan; blocks [SB,SB+RB): reduce previous layer's pool scratch
__global__ void k_scan(const int* __restrict__ deg,
                       int* __restrict__ offs, float* __restrict__ dinv,
                       int* __restrict__ ghist, int* __restrict__ selbuf,
                       int* __restrict__ lbsum, int* __restrict__ lbflag,
                       const float* __restrict__ scr, float* __restrict__ rbuf,
                       int n, int chunk, int epoch, int gbP, int prevL) {
    int b = blockIdx.x, t = threadIdx.x, lane = t & 63, wid = t >> 6;
    if (b >= SB) {
        if (gbP > 0) poolReduce(scr, rbuf, gbP, prevL, b - SB);
        return;
    }
    __shared__ int red[256];
    __shared__ int s_excl;
    __shared__ int wsum[4];
    __shared__ int s_carry;
    if (b == 0) {
        for (int jj = t; jj < GHN; jj += 256) ghist[jj] = 0;
        if (t == 0) { selbuf[2] = 0; selbuf[5] = 0; }
    }
    int start = b*chunk, end = min(start + chunk, n);
    int s = 0;
    for (int i = start + t; i < end; i += 256) s += deg[i];
    red[t] = s; __syncthreads();
    for (int st = 128; st > 0; st >>= 1) { if (t < st) red[t] += red[t+st]; __syncthreads(); }
    if (t == 0) {
        int total = red[0];
        int e1 = epoch*4 + 1, e2 = epoch*4 + 2;
        __hip_atomic_store(&lbsum[b*2], total, __ATOMIC_RELAXED, __HIP_MEMORY_SCOPE_AGENT);
        __hip_atomic_store(&lbflag[b], e1, __ATOMIC_RELEASE, __HIP_MEMORY_SCOPE_AGENT);
        int excl = 0;
        for (int p = b - 1; p >= 0; ) {
            int f;
            do { f = __hip_atomic_load(&lbflag[p], __ATOMIC_ACQUIRE, __HIP_MEMORY_SCOPE_AGENT); }
            while (f != e1 && f != e2);
            if (f == e2) { excl += __hip_atomic_load(&lbsum[p*2+1], __ATOMIC_RELAXED, __HIP_MEMORY_SCOPE_AGENT); break; }
            excl += __hip_atomic_load(&lbsum[p*2], __ATOMIC_RELAXED, __HIP_MEMORY_SCOPE_AGENT);
            p--;
        }
        __hip_atomic_store(&lbsum[b*2+1], excl + total, __ATOMIC_RELAXED, __HIP_MEMORY_SCOPE_AGENT);
        __hip_atomic_store(&lbflag[b], e2, __ATOMIC_RELEASE, __HIP_MEMORY_SCOPE_AGENT);
        s_excl = excl;
    }
    __syncthreads();
    if (t == 0) s_carry = s_excl;
    __syncthreads();
    for (int base = start; base < end; base += 256) {
        int i = base + t;
        int d = (i < end) ? deg[i] : 0;
        int incl = d;
        for (int off = 1; off < 64; off <<= 1) {
            int o = __shfl_up(incl, off);
            if (lane >= off) incl += o;
        }
        if (lane == 63) wsum[wid] = incl;
        __syncthreads();
        if (t == 0) { int c = s_carry; for (int w = 0; w < 4; w++) { int tmp = wsum[w]; wsum[w] = c; c += tmp; } s_carry = c; }
        __syncthreads();
        int p = wsum[wid] + incl - d;
        if (i < end) {
            offs[i] = p;
            dinv[i] = (d > 0) ? 1.0f/sqrtf((float)d) : 0.0f;
        }
        __syncthreads();
    }
}

// ---------------------------------------------------------------- slim CSR fill (rank-based, no atomics, no LDS)
__global__ __launch_bounds__(128) void k_fill(const int* __restrict__ esrc, const int* __restrict__ edst,
                                              const int* __restrict__ erank, const int* __restrict__ offs,
                                              int* __restrict__ csr, const int* __restrict__ ecnt) {
    int ec = *ecnt;
    for (int e = blockIdx.x*128 + threadIdx.x; e < ec; e += FB*128)
        csr[offs[edst[e]] + erank[e]] = esrc[e];
}

// ---------------------------------------------------------------- layer-0 fused node update
__global__ __launch_bounds__(128) void k_gather0(
    const float* __restrict__ x, const float* __restrict__ W1, const float* __restrict__ V1,
    const float* __restrict__ convb,
    const float* __restrict__ bng, const float* __restrict__ bnb,
    const float* __restrict__ bnm, const float* __restrict__ bnv,
    const float* __restrict__ poolp, const float* __restrict__ pnorm,
    const float* __restrict__ prelua,
    const int* __restrict__ offs, const int* __restrict__ deg, const float* __restrict__ dinv,
    const int* __restrict__ csr,
    float* __restrict__ AGG, float* __restrict__ score, unsigned* __restrict__ keys) {
    int v = blockIdx.x, j = threadIdx.x;
    __shared__ float red[128];
    int off = offs[v], dg = deg[v];
    float accs = 0.0f;
    for (int c = j; c < dg; c += 128) { int s = csr[off + c]; accs += x[s]*dinv[s]; }
    red[j] = accs; __syncthreads();
    for (int st = 64; st > 0; st >>= 1) { if (j < st) red[j] += red[j+st]; __syncthreads(); }
    float aggs = red[0] * dinv[v];
    __syncthreads();
    float h2 = aggs*W1[j] + x[v]*V1[j] + convb[j];
    h2 = fmaxf(h2, 0.0f);
    float scale = bng[j] / sqrtf(bnv[j] + 1e-5f);
    h2 = (h2 - bnm[j])*scale + bnb[j];
    float a = prelua[0];
    h2 = (h2 > 0.0f) ? h2 : a*h2;
    AGG[v*128 + j] = h2;
    red[j] = h2 * poolp[j]; __syncthreads();
    for (int st = 64; st > 0; st >>= 1) { if (j < st) red[j] += red[j+st]; __syncthreads(); }
    if (j == 0) {
        float sc = tanhf(red[0] / pnorm[0]);
        score[v] = sc;
        keys[v]  = orderKey(sc);
    }
}

// ---------------------------------------------------------------- generic fused gather + update + score
__global__ __launch_bounds__(128) void k_gather(
    const float* __restrict__ HW, float* __restrict__ AGG,
    const int* __restrict__ offs, const int* __restrict__ deg, const float* __restrict__ dinv,
    const int* __restrict__ csr,
    const float* __restrict__ bng, const float* __restrict__ bnb,
    const float* __restrict__ bnm, const float* __restrict__ bnv,
    const float* __restrict__ poolp, const float* __restrict__ pnorm,
    const float* __restrict__ prelua,
    float* __restrict__ score, unsigned* __restrict__ keys, int layer) {
    int v = blockIdx.x, j = threadIdx.x;
    __shared__ int   s_src[128];
    __shared__ float s_dv[128];
    __shared__ float red[128];
    int off = offs[v], dg = deg[v];
    float acc = 0.0f;
    for (int base = 0; base < dg; base += 128) {
        int cnt = min(128, dg - base);
        if (j < cnt) { int s = csr[off + base + j]; s_src[j] = s; s_dv[j] = dinv[s]; }
        __syncthreads();
        for (int c = 0; c < cnt; c++) acc += HW[s_src[c]*128 + j] * s_dv[c];
        __syncthreads();
    }
    int gj = layer*128 + j;
    float h2 = AGG[v*128 + j] + acc*dinv[v];
    h2 = fmaxf(h2, 0.0f);
    float scale = bng[gj] / sqrtf(bnv[gj] + 1e-5f);
    h2 = (h2 - bnm[gj])*scale + bnb[gj];
    float a = prelua[0];
    h2 = (h2 > 0.0f) ? h2 : a*h2;
    AGG[v*128 + j] = h2;
    red[j] = h2 * poolp[gj]; __syncthreads();
    for (int st = 64; st > 0; st >>= 1) { if (j < st) red[j] += red[j+st]; __syncthreads(); }
    if (j == 0) {
        float sc = tanhf(red[0] / pnorm[layer]);
        score[v] = sc;
        keys[v]  = orderKey(sc);
    }
}

// ---------------------------------------------------------------- fused top-k, all phases grid-parallel
__global__ __launch_bounds__(1024) void k_topk(const unsigned* __restrict__ keys,
                                               int* __restrict__ gh, int* __restrict__ selbuf,
                                               int* __restrict__ degN,
                                               int* __restrict__ remap, int* __restrict__ keep_ids,
                                               int* __restrict__ bar, int n, int kk) {
    __shared__ int lh[2048];
    __shared__ int s_d1, s_r1, s_dA, s_rA, s_dB, s_ntk, s_bC, s_r2, s_lowD, s_lowR;
    __shared__ int s_base, s_cur;
    int t = threadIdx.x, b = blockIdx.x, lane = t & 63;
    int* h1 = gh;
    int* h2 = gh + 2048;
    int* h3 = gh + 4096;
    int* h4 = gh + 5120;
    int* h5 = gh + 5376;

    for (int i = b*1024 + t; i < NMAX; i += TKB*1024) degN[i] = 0;

    int nR = (n + 1023) & ~1023;
    lh[t] = 0; lh[t+1024] = 0;
    __syncthreads();
    for (int i = b*1024 + t; i < nR; i += TKB*1024) {
        bool act = (i < n);
        int bin = act ? (int)(keys[i] >> 21) : 0;
        histAdd(lh, bin, act, 11);
    }
    __syncthreads();
    { int c = lh[t]; if (c) atomicAdd(&h1[t], c); c = lh[t+1024]; if (c) atomicAdd(&h1[t+1024], c); }
    gridbar(&bar[0], TKB);
    suffixSel2048(lh, h1, kk, &s_d1, &s_r1);
    int bstar = s_d1;

    lh[t] = 0; lh[t+1024] = 0;
    __syncthreads();
    for (int i = b*1024 + t; i < nR; i += TKB*1024) {
        bool act = false; int bin = 0;
        if (i < n) { unsigned key = keys[i]; act = ((int)(key >> 21) == bstar); bin = (int)((key >> 10) & 2047); }
        histAdd(lh, act ? bin : 0, act, 11);
    }
    __syncthreads();
    { int c = lh[t]; if (c) atomicAdd(&h2[t], c); c = lh[t+1024]; if (c) atomicAdd(&h2[t+1024], c); }
    gridbar(&bar[1], TKB);
    suffixSel2048(lh, h2, s_r1, &s_dA, &s_rA);
    unsigned top21 = ((unsigned)bstar << 11) | (unsigned)s_dA;

    lh[t] = 0;
    __syncthreads();
    for (int i = b*1024 + t; i < nR; i += TKB*1024) {
        bool act = false; int bin = 0;
        if (i < n) { unsigned key = keys[i]; act = ((key >> 10) == top21); bin = (int)(key & 1023); }
        histAdd(lh, act ? bin : 0, act, 10);
    }
    __syncthreads();
    { int c = lh[t]; if (c) atomicAdd(&h3[t], c); }
    gridbar(&bar[2], TKB);
    suffixSel1024(lh, h3, s_rA, &s_dB, &s_ntk);
    unsigned thresh = (top21 << 10) | (unsigned)s_dB;

    if (t < 256) lh[t] = 0;
    __syncthreads();
    for (int i = b*1024 + t; i < n; i += TKB*1024)
        if (keys[i] == thresh) atomicAdd(&lh[i >> 8], 1);
    __syncthreads();
    if (t < 256) { int c = lh[t]; if (c) atomicAdd(&h4[t], c); }
    gridbar(&bar[3], TKB);
    prefixSel256(lh, h4, s_ntk, &s_bC, &s_r2);
    int bC = s_bC;

    if (t < 256) lh[t] = 0;
    __syncthreads();
    for (int i = b*1024 + t; i < n; i += TKB*1024)
        if (keys[i] == thresh && (i >> 8) == bC) atomicAdd(&lh[i & 255], 1);
    __syncthreads();
    if (t < 256) { int c = lh[t]; if (c) atomicAdd(&h5[t], c); }
    gridbar(&bar[4], TKB);
    prefixSel256(lh, h5, s_r2, &s_lowD, &s_lowR);
    int cut = (bC << 8) | s_lowD;

    {
        int cnt = 0;
        for (int base = b*1024; base < n; base += TKB*1024) {
            int i = base + t;
            if (i < n) {
                unsigned key = keys[i];
                cnt += (key > thresh) || (key == thresh && i <= cut);
            }
        }
        lh[t] = cnt; __syncthreads();
        for (int st = 512; st > 0; st >>= 1) { if (t < st) lh[t] += lh[t+st]; __syncthreads(); }
        if (t == 0) { s_base = atomicAdd(&selbuf[5], lh[0]); s_cur = 0; }
        __syncthreads();
        for (int base = b*1024; base < n; base += TKB*1024) {
            int i = base + t;
            bool keep = false;
            if (i < n) {
                unsigned key = keys[i];
                keep = (key > thresh) || (key == thresh && i <= cut);
            }
            unsigned long long m = __ballot(keep);
            int wcnt = __popcll(m);
            int wbase = 0;
            if (lane == 0 && wcnt) wbase = atomicAdd(&s_cur, wcnt);
            wbase = __shfl(wbase, 0);
            if (keep) {
                int slot = s_base + wbase + __popcll(m & ((1ULL << lane) - 1));
                remap[i] = slot; keep_ids[slot] = i;
            } else if (i < n) remap[i] = -1;
        }
    }
}

// ---------------------------------------------------------------- fused pool stats + next-layer GEMM + edge compact
// blocks [0,gb): stage pooled rows into LDS (stats fold free) + gemm for layer i+1
// blocks [gb,gb+EBLK): edge remap/compact (+next-layer degree/rank)
__global__ __launch_bounds__(128) void k_poolgemm(
        const float* __restrict__ AGGc, const float* __restrict__ score,
        const int* __restrict__ keep_ids, const int* __restrict__ remap,
        float* __restrict__ scr,
        const int* __restrict__ esrcP, const int* __restrict__ edstP,
        int* __restrict__ esrcN, int* __restrict__ edstN, int* __restrict__ erankN,
        const int* __restrict__ ecntP, int* __restrict__ ecntN, int* __restrict__ degN,
        const float* __restrict__ W, const float* __restrict__ V, const float* __restrict__ bias,
        float* __restrict__ HW, float* __restrict__ AGGn, int k, int gb, int do_gemm) {
    int b = blockIdx.x, t = threadIdx.x;
    __shared__ __align__(16) float ht[128*36];   // 18.4 KB -> 8 blocks/CU
    if (b < gb) {
        int v0 = b * GRB;
        float mx = -3.402823e38f, sm = 0.f;
        for (int it = 0; it < GRB; it++) {
            int r = v0 + it;
            bool valid = (r < k);
            int vv = keep_ids[valid ? r : (k - 1)];
            float val = AGGc[(size_t)vv*128 + t] * score[vv];
            if (!valid) val = 0.f;
            ht[t*36 + it] = val;
            if (valid) { mx = fmaxf(mx, val); sm += val; }
        }
        scr[b*256 + t]       = mx;   // thread t owns channel t
        scr[b*256 + 128 + t] = sm;
        if (!do_gemm) return;
        __syncthreads();
        float accW[GRB], accV[GRB];
        #pragma unroll
        for (int r = 0; r < GRB; r++) { accW[r] = 0.0f; accV[r] = 0.0f; }
        #pragma unroll 2
        for (int kk = 0; kk < 128; kk++) {
            float mw = W[kk*128 + t];
            float mv = V[kk*128 + t];
            const float* hp = &ht[kk*36];
            #pragma unroll
            for (int r4 = 0; r4 < GRB; r4 += 4) {
                float4 hq = *(const float4*)(hp + r4);
                accW[r4+0] += hq.x*mw;  accV[r4+0] += hq.x*mv;
                accW[r4+1] += hq.y*mw;  accV[r4+1] += hq.y*mv;
                accW[r4+2] += hq.z*mw;  accV[r4+2] += hq.z*mv;
                accW[r4+3] += hq.w*mw;  accV[r4+3] += hq.w*mv;
            }
        }
        float bb = bias[t];
        for (int r = 0; r < GRB; r++) {
            int v = v0 + r;
            if (v >= k) break;
            HW[(size_t)v*128 + t]   = accW[r];
            AGGn[(size_t)v*128 + t] = accV[r] + bb;
        }
    } else {
        int eb = b - gb, lane = t & 63;
        int ec = *ecntP;
        int* red = (int*)ht;
        __shared__ int s_base, s_cur;
        int cnt = 0;
        for (int base = eb*128; base < ec; base += EBLK*128) {
            int e = base + t;
            if (e < ec) {
                int ns = remap[esrcP[e]], nd = remap[edstP[e]];
                cnt += (ns >= 0 && nd >= 0);
            }
        }
        red[t] = cnt; __syncthreads();
        for (int st = 64; st > 0; st >>= 1) { if (t < st) red[t] += red[t+st]; __syncthreads(); }
        if (t == 0) { s_base = atomicAdd(ecntN, red[0]); s_cur = 0; }
        __syncthreads();
        for (int base = eb*128; base < ec; base += EBLK*128) {
            int e = base + t;
            bool keep = false; int ns = 0, nd = 0;
            if (e < ec) {
                ns = remap[esrcP[e]]; nd = remap[edstP[e]];
                keep = (ns >= 0 && nd >= 0);
            }
            unsigned long long m = __ballot(keep);
            int wcnt = __popcll(m);
            int wbase = 0;
            if (lane == 0 && wcnt) wbase = atomicAdd(&s_cur, wcnt);
            wbase = __shfl(wbase, 0);
            if (keep) {
                int pos = s_base + wbase + __popcll(m & ((1ULL << lane) - 1));
                esrcN[pos] = ns; edstN[pos] = nd;
                erankN[pos] = atomicAdd(&degN[nd], 1);
            }
        }
    }
}

// ---------------------------------------------------------------- final-layer scratch reduce
__global__ void k_pred(const float* __restrict__ scr, float* __restrict__ rbuf, int gbP, int L) {
    poolReduce(scr, rbuf, gbP, L, blockIdx.x);
}

// ---------------------------------------------------------------- MLP head
__global__ __launch_bounds__(320) void k_lin1(const float* __restrict__ rbuf,
                                              const float* __restrict__ w1,
                                              float* __restrict__ z1part) {
    int b = blockIdx.x, t = threadIdx.x;
    int j = t*4;
    float4 acc = make_float4(0.f, 0.f, 0.f, 0.f);
    int i0 = b*40;
    for (int r = 0; r < 40; r++) {
        int i = i0 + r;
        float rv = rbuf[i];
        if (i & 128) rv *= c_invk[i >> 8];
        float4 w = *(const float4*)(w1 + (size_t)i*1280 + j);
        acc.x += rv*w.x; acc.y += rv*w.y; acc.z += rv*w.z; acc.w += rv*w.w;
    }
    *(float4*)(z1part + b*1280 + j) = acc;
}

__global__ __launch_bounds__(320) void k_lin2(const float* __restrict__ z1part,
                                              const float* __restrict__ b1,
                                              const float* __restrict__ w2, const float* __restrict__ b2,
                                              const float* __restrict__ prelua, float* __restrict__ out) {
    int t = threadIdx.x, lane = t & 63, wid = t >> 6;
    float a = prelua[0];
    int j = t*4;
    float4 acc = make_float4(0.f, 0.f, 0.f, 0.f);
    for (int p = 0; p < LIN1B; p++) {
        float4 v = *(const float4*)(z1part + p*1280 + j);
        acc.x += v.x; acc.y += v.y; acc.z += v.z; acc.w += v.w;
    }
    float4 bb = *(const float4*)(b1 + j);
    float z0 = acc.x + bb.x; z0 = z0 > 0.f ? z0 : a*z0;
    float z1 = acc.y + bb.y; z1 = z1 > 0.f ? z1 : a*z1;
    float z2 = acc.z + bb.z; z2 = z2 > 0.f ? z2 : a*z2;
    float z3 = acc.w + bb.w; z3 = z3 > 0.f ? z3 : a*z3;
    float s[8];
    #pragma unroll
    for (int o = 0; o < 8; o++)
        s[o] = z0*w2[(j+0)*8+o] + z1*w2[(j+1)*8+o] + z2*w2[(j+2)*8+o] + z3*w2[(j+3)*8+o];
    #pragma unroll
    for (int off = 32; off > 0; off >>= 1)
        #pragma unroll
        for (int o = 0; o < 8; o++) s[o] += __shfl_down(s[o], off);
    __shared__ float sred[5][8];
    if (lane == 0)
        for (int o = 0; o < 8; o++) sred[wid][o] = s[o];
    __syncthreads();
    if (t == 0) {
        float zo[8];
        for (int o = 0; o < 8; o++) {
            float z = sred[0][o]+sred[1][o]+sred[2][o]+sred[3][o]+sred[4][o] + b2[o];
            zo[o] = z > 0.f ? z : a*z;
        }
        float mn = zo[0];
        for (int o = 1; o < 8; o++) mn = fminf(mn, zo[o]);
        float v[8], mx = -3.402823e38f;
        for (int o = 0; o < 8; o++) { v[o] = zo[o] - mn; mx = fmaxf(mx, v[o]); }
        float sm = 0.f;
        for (int o = 0; o < 8; o++) { v[o] = v[o] / mx; sm += v[o]; }
        for (int o = 0; o < 8; o++) out[o] = v[o] / sm;
    }
}

// ---------------------------------------------------------------- launch
extern "C" void kernel_launch(void* const* d_in, const int* in_sizes, int n_in,
                              void* d_out, int out_size, void* d_ws, size_t ws_size,
                              hipStream_t stream) {
    const float* x      = (const float*)d_in[0];
    const int*   eidx   = (const int*)  d_in[1];
    const float* W1     = (const float*)d_in[2];
    const float* V1     = (const float*)d_in[3];
    const float* Ws     = (const float*)d_in[4];
    const float* Vs     = (const float*)d_in[5];
    const float* convb  = (const float*)d_in[6];
    const float* bng    = (const float*)d_in[7];
    const float* bnb    = (const float*)d_in[8];
    const float* bnm    = (const float*)d_in[9];
    const float* bnv    = (const float*)d_in[10];
    const float* poolp  = (const float*)d_in[11];
    const float* prelua = (const float*)d_in[12];
    const float* w1     = (const float*)d_in[13];
    const float* b1     = (const float*)d_in[14];
    const float* w2     = (const float*)d_in[15];
    const float* b2     = (const float*)d_in[16];
    float* out = (float*)d_out;

    float* wsf  = (float*)d_ws;
    float* aggA   = wsf;                          // NMAX*128
    float* aggB   = aggA  + (size_t)NMAX*128;
    float* HW     = aggB  + (size_t)NMAX*128;
    float* dinv   = HW    + (size_t)NMAX*128;
    float* score  = dinv  + NMAX;
    float* rbuf   = score + NMAX;
    float* pnorm  = rbuf  + 2560;
    float* z1part = pnorm + 16;                   // LIN1B*1280
    float* scr    = z1part + LIN1B*1280;          // GBMAX*256
    unsigned* keys = (unsigned*)(scr + GBMAX*256);
    int* esrcA  = (int*)(keys + NMAX);
    int* edstA  = esrcA + NEDGE;
    int* erankA = edstA + NEDGE;
    int* esrcB  = erankA + NEDGE;
    int* edstB  = esrcB + NEDGE;
    int* erankB = edstB + NEDGE;
    int* csr    = erankB + NEDGE;
    int* degA   = csr   + NEDGE;
    int* degB   = degA  + NMAX;
    int* ghist  = degB  + NMAX;                   // GHN
    int* offs   = ghist + GHN;
    int* remap  = offs  + NMAX;
    int* keep_ids = remap + NMAX;
    int* lbsum  = keep_ids + NMAX;                // SB*2
    int* lbflag = lbsum + SB*2;                   // SB
    int* ecnt   = lbflag + SB;                    // 16
    int* selbuf = ecnt  + 16;                     // 16
    int* tkc    = selbuf + 16;                    // 64

    static const int NS[10] = {40000,32000,25600,20480,16384,13108,10487,8390,6712,5370};
    static const int KS[10] = {32000,25600,20480,16384,13108,10487,8390,6712,5370,4296};

    hipMemsetAsync(degA, 0, (size_t)NMAX*sizeof(int), stream);
    k_init<<<2500, 256, 0, stream>>>(eidx, esrcA, edstA, erankA, poolp, rbuf, pnorm,
                                     ecnt, degA, tkc);

    for (int i = 0; i < 10; i++) {
        int n = NS[i], k = KS[i];
        int chunk = (n + SB - 1) / SB;
        int* esrcP  = (i & 1) ? esrcB  : esrcA;
        int* edstP  = (i & 1) ? edstB  : edstA;
        int* erankP = (i & 1) ? erankB : erankA;
        int* esrcN  = (i & 1) ? esrcA  : esrcB;
        int* edstN  = (i & 1) ? edstA  : edstB;
        int* erankN = (i & 1) ? erankA : erankB;
        int* degP   = (i & 1) ? degB : degA;
        int* degN   = (i & 1) ? degA : degB;
        float* AGGc = (i & 1) ? aggB : aggA;      // current layer features
        float* AGGn = (i & 1) ? aggA : aggB;      // next layer buffer

        int gbP = (i == 0) ? 0 : (KS[i-1] + GRB - 1) / GRB;
        k_scan<<<SB + RB, 256, 0, stream>>>(degP, offs, dinv, ghist, selbuf,
                                            lbsum, lbflag, scr, rbuf, n, chunk, i + 1,
                                            gbP, i - 1);

        k_fill<<<FB, 128, 0, stream>>>(esrcP, edstP, erankP, offs, csr, &ecnt[i]);

        if (i == 0) {
            k_gather0<<<n, 128, 0, stream>>>(x, W1, V1, convb,
                                             bng, bnb, bnm, bnv, poolp, pnorm, prelua,
                                             offs, degP, dinv, csr, AGGc, score, keys);
        } else {
            k_gather<<<n, 128, 0, stream>>>(HW, AGGc, offs, degP, dinv, csr,
                                            bng, bnb, bnm, bnv, poolp, pnorm, prelua,
                                            score, keys, i);
        }

        k_topk<<<TKB, 1024, 0, stream>>>(keys, ghist, selbuf, degN,
                                         remap, keep_ids, tkc + i*5, n, k);

        int gb = (k + GRB - 1) / GRB;
        int do_gemm = (i < 9);
        int grid = gb + (do_gemm ? EBLK : 0);
        // gemm computes layer i+1: weights Ws[(i+1)-1] = Ws + i*16384, bias convb+(i+1)*128
        k_poolgemm<<<grid, 128, 0, stream>>>(AGGc, score, keep_ids, remap, scr,
                                             esrcP, edstP, esrcN, edstN, erankN,
                                             &ecnt[i], &ecnt[i+1], degN,
                                             Ws + (size_t)min(i,8)*16384,
                                             Vs + (size_t)min(i,8)*16384,
                                             convb + min(i+1,9)*128,
                                             HW, AGGn, k, gb, do_gemm);
    }

    k_pred<<<RB, 256, 0, stream>>>(scr, rbuf, (KS[9] + GRB - 1) / GRB, 9);
    k_lin1<<<LIN1B, 320, 0, stream>>>(rbuf, w1, z1part);
    k_lin2<<<1, 320, 0, stream>>>(z1part, b1, w2, b2, prelua, out);
}

// Round 12
// 1245.490 us; speedup vs baseline: 1.3059x; 1.0130x over previous
//
#include <hip/hip_runtime.h>
#include <hip/hip_bf16.h>

#define NEDGE 640000
#define NMAX  40000
#define SB    40      // scan blocks
#define RB    16      // pool-scratch reduce blocks
#define EBLK  512     // edge-compact blocks (128 thr)
#define FB    1280    // fill blocks (128 thr each)
#define LIN1B 64      // lin1 partial blocks
#define GRB   16      // gemm rows per block (16 -> 10.2 KB LDS -> ~15 blocks/CU)
#define HTS   20      // ht row stride (GRB+4, multiple of 4 for float4 reads)
#define TKB   32      // fused top-k blocks
#define GHN   5632    // global hist ints (2048+2048+1024+256+256)
#define GBMAX 2048    // max gemm blocks per layer (ceil(32000/16)=2000)

// ---------------------------------------------------------------- helpers
__device__ inline unsigned orderKey(float s) {
    unsigned b = __float_as_uint(s);
    return (b & 0x80000000u) ? ~b : (b | 0x80000000u);
}

// ballot-dedup LDS histogram insert: O(1) atomics per distinct bin per wave
__device__ inline void histAdd(int* sh, int bin, bool act, int nbits) {
    unsigned long long mm = __ballot(act);
    for (int b = 0; b < nbits; b++) {
        unsigned long long bal = __ballot(act && ((bin >> b) & 1));
        mm &= ((bin >> b) & 1) ? bal : ~bal;
    }
    if (act) {
        int lane = threadIdx.x & 63;
        int leader = __ffsll(mm) - 1;
        if (lane == leader) atomicAdd(&sh[bin], __popcll(mm));
    }
}

// grid barrier for co-resident blocks (fresh counter per use, zeroed in k_init)
__device__ inline void gridbar(int* ctr, int target) {
    __syncthreads();
    if (threadIdx.x == 0) {
        __threadfence();
        __hip_atomic_fetch_add(ctr, 1, __ATOMIC_RELEASE, __HIP_MEMORY_SCOPE_AGENT);
        while (__hip_atomic_load(ctr, __ATOMIC_ACQUIRE, __HIP_MEMORY_SCOPE_AGENT) < target)
            __builtin_amdgcn_s_sleep(1);
        __threadfence();
    }
    __syncthreads();
}

__device__ inline void suffixSel2048(int* lh, const int* gh, int rem, int* outD, int* outR) {
    int t = threadIdx.x;
    lh[t] = gh[t]; lh[t+1024] = gh[t+1024];
    __syncthreads();
    for (int off = 1; off < 2048; off <<= 1) {
        int v0 = lh[t]      + ((t+off < 2048)      ? lh[t+off]      : 0);
        int v1 = lh[t+1024] + ((t+1024+off < 2048) ? lh[t+1024+off] : 0);
        __syncthreads();
        lh[t] = v0; lh[t+1024] = v1;
        __syncthreads();
    }
    for (int d = t; d < 2048; d += 1024) {
        int S = lh[d], Sn = (d == 2047) ? 0 : lh[d+1];
        if (S >= rem && Sn < rem) { *outD = d; *outR = rem - Sn; }
    }
    __syncthreads();
}

__device__ inline void suffixSel1024(int* lh, const int* gh, int rem, int* outD, int* outR) {
    int t = threadIdx.x;
    lh[t] = gh[t];
    __syncthreads();
    for (int off = 1; off < 1024; off <<= 1) {
        int v0 = lh[t] + ((t+off < 1024) ? lh[t+off] : 0);
        __syncthreads();
        lh[t] = v0;
        __syncthreads();
    }
    {
        int S = lh[t], Sn = (t == 1023) ? 0 : lh[t+1];
        if (S >= rem && Sn < rem) { *outD = t; *outR = rem - Sn; }
    }
    __syncthreads();
}

__device__ inline void prefixSel256(int* lh, const int* gh, int rem, int* outD, int* outR) {
    int t = threadIdx.x;
    if (t < 256) lh[t] = gh[t];
    __syncthreads();
    for (int off = 1; off < 256; off <<= 1) {
        int v = 0;
        if (t < 256) v = lh[t] + ((t >= off) ? lh[t-off] : 0);
        __syncthreads();
        if (t < 256) lh[t] = v;
        __syncthreads();
    }
    if (t < 256) {
        int P = lh[t], Pp = (t == 0) ? 0 : lh[t-1];
        if (P >= rem && Pp < rem) { *outD = t; *outR = rem - Pp; }
    }
    __syncthreads();
}

// reduce pool-stat scratch (gbP blocks x 256) -> rbuf[L*256 .. +256), 16 blocks x 256 thr
__device__ inline void poolReduce(const float* __restrict__ scr, float* __restrict__ rbuf,
                                  int gbP, int L, int rblk) {
    int t = threadIdx.x;
    int ch = rblk*16 + (t >> 4);
    int l16 = t & 15;
    bool isMax = ch < 128;
    float acc = isMax ? -3.402823e38f : 0.f;
    for (int r = l16; r < gbP; r += 16) {
        float v = scr[r*256 + ch];
        acc = isMax ? fmaxf(acc, v) : (acc + v);
    }
    __shared__ float sred[16][17];
    sred[t >> 4][l16] = acc;
    __syncthreads();
    if (l16 == 0) {
        float a = sred[t >> 4][0];
        for (int q = 1; q < 16; q++) {
            float v = sred[t >> 4][q];
            a = isMax ? fmaxf(a, v) : (a + v);
        }
        rbuf[L*256 + ch] = a;
    }
}

__device__ const float c_invk[10] = {
    1.0f/32000.0f, 1.0f/25600.0f, 1.0f/20480.0f, 1.0f/16384.0f, 1.0f/13108.0f,
    1.0f/10487.0f, 1.0f/8390.0f,  1.0f/6712.0f,  1.0f/5370.0f,  1.0f/4296.0f };

// ---------------------------------------------------------------- init (+ layer-0 degree count + ranks)
__global__ void k_init(const int* __restrict__ eidx, int* __restrict__ esrc,
                       int* __restrict__ edst, int* __restrict__ erank,
                       const float* __restrict__ poolp,
                       float* __restrict__ rbuf, float* __restrict__ pnorm,
                       int* __restrict__ ecnt, int* __restrict__ degA,
                       int* __restrict__ tkc) {
    int b = blockIdx.x, t = threadIdx.x;
    if (b < 10) {
        rbuf[b*256 + t] = (t < 128) ? -3.402823e38f : 0.0f;
        __shared__ float red[256];
        float v = 0.0f;
        if (t < 128) { float pv = poolp[b*128 + t]; v = pv*pv; }
        red[t] = v; __syncthreads();
        for (int s = 128; s > 0; s >>= 1) { if (t < s) red[t] += red[t+s]; __syncthreads(); }
        if (t == 0) pnorm[b] = sqrtf(red[0]);
    }
    if (b == 10 && t < 16) ecnt[t] = (t == 0) ? NEDGE : 0;
    if (b == 11 && t < 64) tkc[t] = 0;
    int e = b*256 + t;
    if (e < NEDGE) {
        int d = eidx[NEDGE + e];
        esrc[e] = eidx[e]; edst[e] = d;
        erank[e] = atomicAdd(&degA[d], 1);
    }
}

// ---------------------------------------------------------------- fused single-pass scan (decoupled lookback)
// blocks [0,SB): scan; blocks [SB,SB+RB): reduce previous layer's pool scratch
__global__ void k_scan(const int* __restrict__ deg,
                       int* __restrict__ offs, float* __restrict__ dinv,
                       int* __restrict__ ghist, int* __restrict__ selbuf,
                       int* __restrict__ lbsum, int* __restrict__ lbflag,
                       const float* __restrict__ scr, float* __restrict__ rbuf,
                       int n, int chunk, int epoch, int gbP, int prevL) {
    int b = blockIdx.x, t = threadIdx.x, lane = t & 63, wid = t >> 6;
    if (b >= SB) {
        if (gbP > 0) poolReduce(scr, rbuf, gbP, prevL, b - SB);
        return;
    }
    __shared__ int red[256];
    __shared__ int s_excl;
    __shared__ int wsum[4];
    __shared__ int s_carry;
    if (b == 0) {
        for (int jj = t; jj < GHN; jj += 256) ghist[jj] = 0;
        if (t == 0) { selbuf[2] = 0; selbuf[5] = 0; }
    }
    int start = b*chunk, end = min(start + chunk, n);
    int s = 0;
    for (int i = start + t; i < end; i += 256) s += deg[i];
    red[t] = s; __syncthreads();
    for (int st = 128; st > 0; st >>= 1) { if (t < st) red[t] += red[t+st]; __syncthreads(); }
    if (t == 0) {
        int total = red[0];
        int e1 = epoch*4 + 1, e2 = epoch*4 + 2;
        __hip_atomic_store(&lbsum[b*2], total, __ATOMIC_RELAXED, __HIP_MEMORY_SCOPE_AGENT);
        __hip_atomic_store(&lbflag[b], e1, __ATOMIC_RELEASE, __HIP_MEMORY_SCOPE_AGENT);
        int excl = 0;
        for (int p = b - 1; p >= 0; ) {
            int f;
            do { f = __hip_atomic_load(&lbflag[p], __ATOMIC_ACQUIRE, __HIP_MEMORY_SCOPE_AGENT); }
            while (f != e1 && f != e2);
            if (f == e2) { excl += __hip_atomic_load(&lbsum[p*2+1], __ATOMIC_RELAXED, __HIP_MEMORY_SCOPE_AGENT); break; }
            excl += __hip_atomic_load(&lbsum[p*2], __ATOMIC_RELAXED, __HIP_MEMORY_SCOPE_AGENT);
            p--;
        }
        __hip_atomic_store(&lbsum[b*2+1], excl + total, __ATOMIC_RELAXED, __HIP_MEMORY_SCOPE_AGENT);
        __hip_atomic_store(&lbflag[b], e2, __ATOMIC_RELEASE, __HIP_MEMORY_SCOPE_AGENT);
        s_excl = excl;
    }
    __syncthreads();
    if (t == 0) s_carry = s_excl;
    __syncthreads();
    for (int base = start; base < end; base += 256) {
        int i = base + t;
        int d = (i < end) ? deg[i] : 0;
        int incl = d;
        for (int off = 1; off < 64; off <<= 1) {
            int o = __shfl_up(incl, off);
            if (lane >= off) incl += o;
        }
        if (lane == 63) wsum[wid] = incl;
        __syncthreads();
        if (t == 0) { int c = s_carry; for (int w = 0; w < 4; w++) { int tmp = wsum[w]; wsum[w] = c; c += tmp; } s_carry = c; }
        __syncthreads();
        int p = wsum[wid] + incl - d;
        if (i < end) {
            offs[i] = p;
            dinv[i] = (d > 0) ? 1.0f/sqrtf((float)d) : 0.0f;
        }
        __syncthreads();
    }
}

// ---------------------------------------------------------------- slim CSR fill (rank-based, no atomics, no LDS)
__global__ __launch_bounds__(128) void k_fill(const int* __restrict__ esrc, const int* __restrict__ edst,
                                              const int* __restrict__ erank, const int* __restrict__ offs,
                                              int* __restrict__ csr, const int* __restrict__ ecnt) {
    int ec = *ecnt;
    for (int e = blockIdx.x*128 + threadIdx.x; e < ec; e += FB*128)
        csr[offs[edst[e]] + erank[e]] = esrc[e];
}

// ---------------------------------------------------------------- layer-0 fused node update
__global__ __launch_bounds__(128) void k_gather0(
    const float* __restrict__ x, const float* __restrict__ W1, const float* __restrict__ V1,
    const float* __restrict__ convb,
    const float* __restrict__ bng, const float* __restrict__ bnb,
    const float* __restrict__ bnm, const float* __restrict__ bnv,
    const float* __restrict__ poolp, const float* __restrict__ pnorm,
    const float* __restrict__ prelua,
    const int* __restrict__ offs, const int* __restrict__ deg, const float* __restrict__ dinv,
    const int* __restrict__ csr,
    float* __restrict__ AGG, float* __restrict__ score, unsigned* __restrict__ keys) {
    int v = blockIdx.x, j = threadIdx.x;
    __shared__ float red[128];
    int off = offs[v], dg = deg[v];
    float accs = 0.0f;
    for (int c = j; c < dg; c += 128) { int s = csr[off + c]; accs += x[s]*dinv[s]; }
    red[j] = accs; __syncthreads();
    for (int st = 64; st > 0; st >>= 1) { if (j < st) red[j] += red[j+st]; __syncthreads(); }
    float aggs = red[0] * dinv[v];
    __syncthreads();
    float h2 = aggs*W1[j] + x[v]*V1[j] + convb[j];
    h2 = fmaxf(h2, 0.0f);
    float scale = bng[j] / sqrtf(bnv[j] + 1e-5f);
    h2 = (h2 - bnm[j])*scale + bnb[j];
    float a = prelua[0];
    h2 = (h2 > 0.0f) ? h2 : a*h2;
    AGG[v*128 + j] = h2;
    red[j] = h2 * poolp[j]; __syncthreads();
    for (int st = 64; st > 0; st >>= 1) { if (j < st) red[j] += red[j+st]; __syncthreads(); }
    if (j == 0) {
        float sc = tanhf(red[0] / pnorm[0]);
        score[v] = sc;
        keys[v]  = orderKey(sc);
    }
}

// ---------------------------------------------------------------- generic fused gather + update + score
__global__ __launch_bounds__(128) void k_gather(
    const float* __restrict__ HW, float* __restrict__ AGG,
    const int* __restrict__ offs, const int* __restrict__ deg, const float* __restrict__ dinv,
    const int* __restrict__ csr,
    const float* __restrict__ bng, const float* __restrict__ bnb,
    const float* __restrict__ bnm, const float* __restrict__ bnv,
    const float* __restrict__ poolp, const float* __restrict__ pnorm,
    const float* __restrict__ prelua,
    float* __restrict__ score, unsigned* __restrict__ keys, int layer) {
    int v = blockIdx.x, j = threadIdx.x;
    __shared__ int   s_src[128];
    __shared__ float s_dv[128];
    __shared__ float red[128];
    int off = offs[v], dg = deg[v];
    float acc = 0.0f;
    for (int base = 0; base < dg; base += 128) {
        int cnt = min(128, dg - base);
        if (j < cnt) { int s = csr[off + base + j]; s_src[j] = s; s_dv[j] = dinv[s]; }
        __syncthreads();
        for (int c = 0; c < cnt; c++) acc += HW[s_src[c]*128 + j] * s_dv[c];
        __syncthreads();
    }
    int gj = layer*128 + j;
    float h2 = AGG[v*128 + j] + acc*dinv[v];
    h2 = fmaxf(h2, 0.0f);
    float scale = bng[gj] / sqrtf(bnv[gj] + 1e-5f);
    h2 = (h2 - bnm[gj])*scale + bnb[gj];
    float a = prelua[0];
    h2 = (h2 > 0.0f) ? h2 : a*h2;
    AGG[v*128 + j] = h2;
    red[j] = h2 * poolp[gj]; __syncthreads();
    for (int st = 64; st > 0; st >>= 1) { if (j < st) red[j] += red[j+st]; __syncthreads(); }
    if (j == 0) {
        float sc = tanhf(red[0] / pnorm[layer]);
        score[v] = sc;
        keys[v]  = orderKey(sc);
    }
}

// ---------------------------------------------------------------- fused top-k, all phases grid-parallel
__global__ __launch_bounds__(1024) void k_topk(const unsigned* __restrict__ keys,
                                               int* __restrict__ gh, int* __restrict__ selbuf,
                                               int* __restrict__ degN,
                                               int* __restrict__ remap, int* __restrict__ keep_ids,
                                               int* __restrict__ bar, int n, int kk) {
    __shared__ int lh[2048];
    __shared__ int s_d1, s_r1, s_dA, s_rA, s_dB, s_ntk, s_bC, s_r2, s_lowD, s_lowR;
    __shared__ int s_base, s_cur;
    int t = threadIdx.x, b = blockIdx.x, lane = t & 63;
    int* h1 = gh;
    int* h2 = gh + 2048;
    int* h3 = gh + 4096;
    int* h4 = gh + 5120;
    int* h5 = gh + 5376;

    for (int i = b*1024 + t; i < NMAX; i += TKB*1024) degN[i] = 0;

    int nR = (n + 1023) & ~1023;
    lh[t] = 0; lh[t+1024] = 0;
    __syncthreads();
    for (int i = b*1024 + t; i < nR; i += TKB*1024) {
        bool act = (i < n);
        int bin = act ? (int)(keys[i] >> 21) : 0;
        histAdd(lh, bin, act, 11);
    }
    __syncthreads();
    { int c = lh[t]; if (c) atomicAdd(&h1[t], c); c = lh[t+1024]; if (c) atomicAdd(&h1[t+1024], c); }
    gridbar(&bar[0], TKB);
    suffixSel2048(lh, h1, kk, &s_d1, &s_r1);
    int bstar = s_d1;

    lh[t] = 0; lh[t+1024] = 0;
    __syncthreads();
    for (int i = b*1024 + t; i < nR; i += TKB*1024) {
        bool act = false; int bin = 0;
        if (i < n) { unsigned key = keys[i]; act = ((int)(key >> 21) == bstar); bin = (int)((key >> 10) & 2047); }
        histAdd(lh, act ? bin : 0, act, 11);
    }
    __syncthreads();
    { int c = lh[t]; if (c) atomicAdd(&h2[t], c); c = lh[t+1024]; if (c) atomicAdd(&h2[t+1024], c); }
    gridbar(&bar[1], TKB);
    suffixSel2048(lh, h2, s_r1, &s_dA, &s_rA);
    unsigned top21 = ((unsigned)bstar << 11) | (unsigned)s_dA;

    lh[t] = 0;
    __syncthreads();
    for (int i = b*1024 + t; i < nR; i += TKB*1024) {
        bool act = false; int bin = 0;
        if (i < n) { unsigned key = keys[i]; act = ((key >> 10) == top21); bin = (int)(key & 1023); }
        histAdd(lh, act ? bin : 0, act, 10);
    }
    __syncthreads();
    { int c = lh[t]; if (c) atomicAdd(&h3[t], c); }
    gridbar(&bar[2], TKB);
    suffixSel1024(lh, h3, s_rA, &s_dB, &s_ntk);
    unsigned thresh = (top21 << 10) | (unsigned)s_dB;

    if (t < 256) lh[t] = 0;
    __syncthreads();
    for (int i = b*1024 + t; i < n; i += TKB*1024)
        if (keys[i] == thresh) atomicAdd(&lh[i >> 8], 1);
    __syncthreads();
    if (t < 256) { int c = lh[t]; if (c) atomicAdd(&h4[t], c); }
    gridbar(&bar[3], TKB);
    prefixSel256(lh, h4, s_ntk, &s_bC, &s_r2);
    int bC = s_bC;

    if (t < 256) lh[t] = 0;
    __syncthreads();
    for (int i = b*1024 + t; i < n; i += TKB*1024)
        if (keys[i] == thresh && (i >> 8) == bC) atomicAdd(&lh[i & 255], 1);
    __syncthreads();
    if (t < 256) { int c = lh[t]; if (c) atomicAdd(&h5[t], c); }
    gridbar(&bar[4], TKB);
    prefixSel256(lh, h5, s_r2, &s_lowD, &s_lowR);
    int cut = (bC << 8) | s_lowD;

    {
        int cnt = 0;
        for (int base = b*1024; base < n; base += TKB*1024) {
            int i = base + t;
            if (i < n) {
                unsigned key = keys[i];
                cnt += (key > thresh) || (key == thresh && i <= cut);
            }
        }
        lh[t] = cnt; __syncthreads();
        for (int st = 512; st > 0; st >>= 1) { if (t < st) lh[t] += lh[t+st]; __syncthreads(); }
        if (t == 0) { s_base = atomicAdd(&selbuf[5], lh[0]); s_cur = 0; }
        __syncthreads();
        for (int base = b*1024; base < n; base += TKB*1024) {
            int i = base + t;
            bool keep = false;
            if (i < n) {
                unsigned key = keys[i];
                keep = (key > thresh) || (key == thresh && i <= cut);
            }
            unsigned long long m = __ballot(keep);
            int wcnt = __popcll(m);
            int wbase = 0;
            if (lane == 0 && wcnt) wbase = atomicAdd(&s_cur, wcnt);
            wbase = __shfl(wbase, 0);
            if (keep) {
                int slot = s_base + wbase + __popcll(m & ((1ULL << lane) - 1));
                remap[i] = slot; keep_ids[slot] = i;
            } else if (i < n) remap[i] = -1;
        }
    }
}

// ---------------------------------------------------------------- fused pool stats + next-layer GEMM + edge compact
// blocks [0,gb): stage pooled rows into LDS (stats fold free) + gemm for layer i+1
// blocks [gb,gb+EBLK): edge remap/compact (+next-layer degree/rank)
__global__ __launch_bounds__(128) void k_poolgemm(
        const float* __restrict__ AGGc, const float* __restrict__ score,
        const int* __restrict__ keep_ids, const int* __restrict__ remap,
        float* __restrict__ scr,
        const int* __restrict__ esrcP, const int* __restrict__ edstP,
        int* __restrict__ esrcN, int* __restrict__ edstN, int* __restrict__ erankN,
        const int* __restrict__ ecntP, int* __restrict__ ecntN, int* __restrict__ degN,
        const float* __restrict__ W, const float* __restrict__ V, const float* __restrict__ bias,
        float* __restrict__ HW, float* __restrict__ AGGn, int k, int gb, int do_gemm) {
    int b = blockIdx.x, t = threadIdx.x;
    __shared__ __align__(16) float ht[128*HTS];   // 10.2 KB -> ~15 blocks/CU
    if (b < gb) {
        int v0 = b * GRB;
        float mx = -3.402823e38f, sm = 0.f;
        #pragma unroll
        for (int it = 0; it < GRB; it++) {
            int r = v0 + it;
            bool valid = (r < k);
            int vv = keep_ids[valid ? r : (k - 1)];
            float val = AGGc[(size_t)vv*128 + t] * score[vv];
            if (!valid) val = 0.f;
            ht[t*HTS + it] = val;
            if (valid) { mx = fmaxf(mx, val); sm += val; }
        }
        scr[b*256 + t]       = mx;   // thread t owns channel t
        scr[b*256 + 128 + t] = sm;
        if (!do_gemm) return;
        __syncthreads();
        float accW[GRB], accV[GRB];
        #pragma unroll
        for (int r = 0; r < GRB; r++) { accW[r] = 0.0f; accV[r] = 0.0f; }
        #pragma unroll 4
        for (int kk = 0; kk < 128; kk++) {
            float mw = W[kk*128 + t];
            float mv = V[kk*128 + t];
            const float* hp = &ht[kk*HTS];
            #pragma unroll
            for (int r4 = 0; r4 < GRB; r4 += 4) {
                float4 hq = *(const float4*)(hp + r4);
                accW[r4+0] += hq.x*mw;  accV[r4+0] += hq.x*mv;
                accW[r4+1] += hq.y*mw;  accV[r4+1] += hq.y*mv;
                accW[r4+2] += hq.z*mw;  accV[r4+2] += hq.z*mv;
                accW[r4+3] += hq.w*mw;  accV[r4+3] += hq.w*mv;
            }
        }
        float bb = bias[t];
        for (int r = 0; r < GRB; r++) {
            int v = v0 + r;
            if (v >= k) break;
            HW[(size_t)v*128 + t]   = accW[r];
            AGGn[(size_t)v*128 + t] = accV[r] + bb;
        }
    } else {
        int eb = b - gb, lane = t & 63;
        int ec = *ecntP;
        int* red = (int*)ht;
        __shared__ int s_base, s_cur;
        int cnt = 0;
        for (int base = eb*128; base < ec; base += EBLK*128) {
            int e = base + t;
            if (e < ec) {
                int ns = remap[esrcP[e]], nd = remap[edstP[e]];
                cnt += (ns >= 0 && nd >= 0);
            }
        }
        red[t] = cnt; __syncthreads();
        for (int st = 64; st > 0; st >>= 1) { if (t < st) red[t] += red[t+st]; __syncthreads(); }
        if (t == 0) { s_base = atomicAdd(ecntN, red[0]); s_cur = 0; }
        __syncthreads();
        for (int base = eb*128; base < ec; base += EBLK*128) {
            int e = base + t;
            bool keep = false; int ns = 0, nd = 0;
            if (e < ec) {
                ns = remap[esrcP[e]]; nd = remap[edstP[e]];
                keep = (ns >= 0 && nd >= 0);
            }
            unsigned long long m = __ballot(keep);
            int wcnt = __popcll(m);
            int wbase = 0;
            if (lane == 0 && wcnt) wbase = atomicAdd(&s_cur, wcnt);
            wbase = __shfl(wbase, 0);
            if (keep) {
                int pos = s_base + wbase + __popcll(m & ((1ULL << lane) - 1));
                esrcN[pos] = ns; edstN[pos] = nd;
                erankN[pos] = atomicAdd(&degN[nd], 1);
            }
        }
    }
}

// ---------------------------------------------------------------- final-layer scratch reduce
__global__ void k_pred(const float* __restrict__ scr, float* __restrict__ rbuf, int gbP, int L) {
    poolReduce(scr, rbuf, gbP, L, blockIdx.x);
}

// ---------------------------------------------------------------- MLP head
__global__ __launch_bounds__(320) void k_lin1(const float* __restrict__ rbuf,
                                              const float* __restrict__ w1,
                                              float* __restrict__ z1part) {
    int b = blockIdx.x, t = threadIdx.x;
    int j = t*4;
    float4 acc = make_float4(0.f, 0.f, 0.f, 0.f);
    int i0 = b*40;
    for (int r = 0; r < 40; r++) {
        int i = i0 + r;
        float rv = rbuf[i];
        if (i & 128) rv *= c_invk[i >> 8];
        float4 w = *(const float4*)(w1 + (size_t)i*1280 + j);
        acc.x += rv*w.x; acc.y += rv*w.y; acc.z += rv*w.z; acc.w += rv*w.w;
    }
    *(float4*)(z1part + b*1280 + j) = acc;
}

__global__ __launch_bounds__(320) void k_lin2(const float* __restrict__ z1part,
                                              const float* __restrict__ b1,
                                              const float* __restrict__ w2, const float* __restrict__ b2,
                                              const float* __restrict__ prelua, float* __restrict__ out) {
    int t = threadIdx.x, lane = t & 63, wid = t >> 6;
    float a = prelua[0];
    int j = t*4;
    float4 acc = make_float4(0.f, 0.f, 0.f, 0.f);
    for (int p = 0; p < LIN1B; p++) {
        float4 v = *(const float4*)(z1part + p*1280 + j);
        acc.x += v.x; acc.y += v.y; acc.z += v.z; acc.w += v.w;
    }
    float4 bb = *(const float4*)(b1 + j);
    float z0 = acc.x + bb.x; z0 = z0 > 0.f ? z0 : a*z0;
    float z1 = acc.y + bb.y; z1 = z1 > 0.f ? z1 : a*z1;
    float z2 = acc.z + bb.z; z2 = z2 > 0.f ? z2 : a*z2;
    float z3 = acc.w + bb.w; z3 = z3 > 0.f ? z3 : a*z3;
    float s[8];
    #pragma unroll
    for (int o = 0; o < 8; o++)
        s[o] = z0*w2[(j+0)*8+o] + z1*w2[(j+1)*8+o] + z2*w2[(j+2)*8+o] + z3*w2[(j+3)*8+o];
    #pragma unroll
    for (int off = 32; off > 0; off >>= 1)
        #pragma unroll
        for (int o = 0; o < 8; o++) s[o] += __shfl_down(s[o], off);
    __shared__ float sred[5][8];
    if (lane == 0)
        for (int o = 0; o < 8; o++) sred[wid][o] = s[o];
    __syncthreads();
    if (t == 0) {
        float zo[8];
        for (int o = 0; o < 8; o++) {
            float z = sred[0][o]+sred[1][o]+sred[2][o]+sred[3][o]+sred[4][o] + b2[o];
            zo[o] = z > 0.f ? z : a*z;
        }
        float mn = zo[0];
        for (int o = 1; o < 8; o++) mn = fminf(mn, zo[o]);
        float v[8], mx = -3.402823e38f;
        for (int o = 0; o < 8; o++) { v[o] = zo[o] - mn; mx = fmaxf(mx, v[o]); }
        float sm = 0.f;
        for (int o = 0; o < 8; o++) { v[o] = v[o] / mx; sm += v[o]; }
        for (int o = 0; o < 8; o++) out[o] = v[o] / sm;
    }
}

// ---------------------------------------------------------------- launch
extern "C" void kernel_launch(void* const* d_in, const int* in_sizes, int n_in,
                              void* d_out, int out_size, void* d_ws, size_t ws_size,
                              hipStream_t stream) {
    const float* x      = (const float*)d_in[0];
    const int*   eidx   = (const int*)  d_in[1];
    const float* W1     = (const float*)d_in[2];
    const float* V1     = (const float*)d_in[3];
    const float* Ws     = (const float*)d_in[4];
    const float* Vs     = (const float*)d_in[5];
    const float* convb  = (const float*)d_in[6];
    const float* bng    = (const float*)d_in[7];
    const float* bnb    = (const float*)d_in[8];
    const float* bnm    = (const float*)d_in[9];
    const float* bnv    = (const float*)d_in[10];
    const float* poolp  = (const float*)d_in[11];
    const float* prelua = (const float*)d_in[12];
    const float* w1     = (const float*)d_in[13];
    const float* b1     = (const float*)d_in[14];
    const float* w2     = (const float*)d_in[15];
    const float* b2     = (const float*)d_in[16];
    float* out = (float*)d_out;

    float* wsf  = (float*)d_ws;
    float* aggA   = wsf;                          // NMAX*128
    float* aggB   = aggA  + (size_t)NMAX*128;
    float* HW     = aggB  + (size_t)NMAX*128;
    float* dinv   = HW    + (size_t)NMAX*128;
    float* score  = dinv  + NMAX;
    float* rbuf   = score + NMAX;
    float* pnorm  = rbuf  + 2560;
    float* z1part = pnorm + 16;                   // LIN1B*1280
    float* scr    = z1part + LIN1B*1280;          // GBMAX*256
    unsigned* keys = (unsigned*)(scr + (size_t)GBMAX*256);
    int* esrcA  = (int*)(keys + NMAX);
    int* edstA  = esrcA + NEDGE;
    int* erankA = edstA + NEDGE;
    int* esrcB  = erankA + NEDGE;
    int* edstB  = esrcB + NEDGE;
    int* erankB = edstB + NEDGE;
    int* csr    = erankB + NEDGE;
    int* degA   = csr   + NEDGE;
    int* degB   = degA  + NMAX;
    int* ghist  = degB  + NMAX;                   // GHN
    int* offs   = ghist + GHN;
    int* remap  = offs  + NMAX;
    int* keep_ids = remap + NMAX;
    int* lbsum  = keep_ids + NMAX;                // SB*2
    int* lbflag = lbsum + SB*2;                   // SB
    int* ecnt   = lbflag + SB;                    // 16
    int* selbuf = ecnt  + 16;                     // 16
    int* tkc    = selbuf + 16;                    // 64

    static const int NS[10] = {40000,32000,25600,20480,16384,13108,10487,8390,6712,5370};
    static const int KS[10] = {32000,25600,20480,16384,13108,10487,8390,6712,5370,4296};

    hipMemsetAsync(degA, 0, (size_t)NMAX*sizeof(int), stream);
    k_init<<<2500, 256, 0, stream>>>(eidx, esrcA, edstA, erankA, poolp, rbuf, pnorm,
                                     ecnt, degA, tkc);

    for (int i = 0; i < 10; i++) {
        int n = NS[i], k = KS[i];
        int chunk = (n + SB - 1) / SB;
        int* esrcP  = (i & 1) ? esrcB  : esrcA;
        int* edstP  = (i & 1) ? edstB  : edstA;
        int* erankP = (i & 1) ? erankB : erankA;
        int* esrcN  = (i & 1) ? esrcA  : esrcB;
        int* edstN  = (i & 1) ? edstA  : edstB;
        int* erankN = (i & 1) ? erankA : erankB;
        int* degP   = (i & 1) ? degB : degA;
        int* degN   = (i & 1) ? degA : degB;
        float* AGGc = (i & 1) ? aggB : aggA;      // current layer features
        float* AGGn = (i & 1) ? aggA : aggB;      // next layer buffer

        int gbP = (i == 0) ? 0 : (KS[i-1] + GRB - 1) / GRB;
        k_scan<<<SB + RB, 256, 0, stream>>>(degP, offs, dinv, ghist, selbuf,
                                            lbsum, lbflag, scr, rbuf, n, chunk, i + 1,
                                            gbP, i - 1);

        k_fill<<<FB, 128, 0, stream>>>(esrcP, edstP, erankP, offs, csr, &ecnt[i]);

        if (i == 0) {
            k_gather0<<<n, 128, 0, stream>>>(x, W1, V1, convb,
                                             bng, bnb, bnm, bnv, poolp, pnorm, prelua,
                                             offs, degP, dinv, csr, AGGc, score, keys);
        } else {
            k_gather<<<n, 128, 0, stream>>>(HW, AGGc, offs, degP, dinv, csr,
                                            bng, bnb, bnm, bnv, poolp, pnorm, prelua,
                                            score, keys, i);
        }

        k_topk<<<TKB, 1024, 0, stream>>>(keys, ghist, selbuf, degN,
                                         remap, keep_ids, tkc + i*5, n, k);

        int gb = (k + GRB - 1) / GRB;
        int do_gemm = (i < 9);
        int grid = gb + (do_gemm ? EBLK : 0);
        // gemm computes layer i+1: weights Ws[(i+1)-1] = Ws + i*16384, bias convb+(i+1)*128
        k_poolgemm<<<grid, 128, 0, stream>>>(AGGc, score, keep_ids, remap, scr,
                                             esrcP, edstP, esrcN, edstN, erankN,
                                             &ecnt[i], &ecnt[i+1], degN,
                                             Ws + (size_t)min(i,8)*16384,
                                             Vs + (size_t)min(i,8)*16384,
                                             convb + min(i+1,9)*128,
                                             HW, AGGn, k, gb, do_gemm);
    }

    k_pred<<<RB, 256, 0, stream>>>(scr, rbuf, (KS[9] + GRB - 1) / GRB, 9);
    k_lin1<<<LIN1B, 320, 0, stream>>>(rbuf, w1, z1part);
    k_lin2<<<1, 320, 0, stream>>>(z1part, b1, w2, b2, prelua, out);
}